// Round 5
// baseline (249.653 us; speedup 1.0000x reference)
//
#include <hip/hip_runtime.h>
#include <math.h>

#define NN 65536
#define MM 16384
#define EE 524288
#define CF 64
#define HD 128
#define OD 256
#define GPB 4   // 64-edge groups per block

typedef __bf16 bf16x8 __attribute__((ext_vector_type(8)));
typedef __bf16 bf16x4 __attribute__((ext_vector_type(4)));
typedef float f32x4 __attribute__((ext_vector_type(4)));

__device__ __forceinline__ unsigned enc_f(float f) {
    unsigned u = __float_as_uint(f);
    return (u & 0x80000000u) ? ~u : (u | 0x80000000u);
}
__device__ __forceinline__ float dec_f(unsigned e) {
    unsigned u = (e & 0x80000000u) ? (e ^ 0x80000000u) : ~e;
    return __uint_as_float(u);
}
#define ENC_NEG_INF 0x007FFFFFu

__device__ __forceinline__ unsigned bf_bits(float f) {
    __bf16 b = (__bf16)f;
    return (unsigned)__builtin_bit_cast(unsigned short, b);
}

__global__ void k_init(unsigned* __restrict__ agg) {
    int i = blockIdx.x * 256 + threadIdx.x;
    if (i < MM * HD) agg[i] = ENC_NEG_INF;
}

__global__ void k_prep(const float* __restrict__ pos, const int* __restrict__ batch,
                       const int* __restrict__ idx, float* __restrict__ out) {
    int m = blockIdx.x * 256 + threadIdx.x;
    if (m >= MM) return;
    int s = idx[m];
    out[MM * OD + m * 3 + 0] = pos[s * 3 + 0];
    out[MM * OD + m * 3 + 1] = pos[s * 3 + 1];
    out[MM * OD + m * 3 + 2] = pos[s * 3 + 2];
    out[MM * OD + MM * 3 + m] = (float)batch[s];
}

// Fused edge kernel.
// edge_in columns (K permuted; weights permuted to match):
// [x: 0-63][pd0,pd1,pd2: 64-66][zero: 67][d0 pairs: 68-87][d1: 88-107][d2: 108-127]
// GEMM1 swapped (W1 as A): D1[n][e] -> hbuf (b64 stores of 4 consecutive n).
// GEMM2 non-swapped (h as A): D2[e][n] -> lane holds 4 consecutive e -> sequential segmax.
__launch_bounds__(256, 3)
__global__ void k_edge(const float* __restrict__ x, const float* __restrict__ pos,
                       const int* __restrict__ idx, const int* __restrict__ row,
                       const int* __restrict__ col,
                       const float* __restrict__ lw1, const float* __restrict__ lb1,
                       const float* __restrict__ lw2, const float* __restrict__ lb2,
                       unsigned* __restrict__ agg) {
    __shared__ __align__(16) __bf16 ein[64][HD];   // 16 KB
    __shared__ __align__(16) __bf16 hbuf[64][HD];  // 16 KB
    __shared__ int srow[2][64];                    // double-buffered
    const int t = threadIdx.x;
    const int lane = t & 63;
    const int wv = t >> 6;
    const int q = lane >> 4;
    const int ln = lane & 15;
    const int lsw = ln & 7;

    // staging identity: this thread always stages edge pe_e, 16-col slice pe_part
    const int pe_e = t >> 2, pe_part = t & 3, pe_esw = pe_e & 7;

    float4 v0, v1, v2, v3;  // prefetched x[col] slice (next group)
    auto issue = [&](int e0) {
        const int c = col[e0 + pe_e];
        const float4* xr = (const float4*)(x + (size_t)c * CF) + pe_part * 4;
        v0 = xr[0]; v1 = xr[1]; v2 = xr[2]; v3 = xr[3];
    };
    auto commit = [&]() {
        bf16x8 pk;
        pk[0] = (__bf16)v0.x; pk[1] = (__bf16)v0.y; pk[2] = (__bf16)v0.z; pk[3] = (__bf16)v0.w;
        pk[4] = (__bf16)v1.x; pk[5] = (__bf16)v1.y; pk[6] = (__bf16)v1.z; pk[7] = (__bf16)v1.w;
        *(bf16x8*)&ein[pe_e][((pe_part * 2 + 0) ^ pe_esw) * 8] = pk;
        pk[0] = (__bf16)v2.x; pk[1] = (__bf16)v2.y; pk[2] = (__bf16)v2.z; pk[3] = (__bf16)v2.w;
        pk[4] = (__bf16)v3.x; pk[5] = (__bf16)v3.y; pk[6] = (__bf16)v3.z; pk[7] = (__bf16)v3.w;
        *(bf16x8*)&ein[pe_e][((pe_part * 2 + 1) ^ pe_esw) * 8] = pk;
    };

    issue(blockIdx.x * GPB * 64);  // group 0, before weight prologue

    // ---- weight fragments: w1f as A (GEMM1), w2f as B (GEMM2); n = wv*32+nt*16+ln ----
    bf16x8 w1f[2][4], w2f[2][4];
    float4 b1q[2];
    float b2s[2];
    #pragma unroll
    for (int nt = 0; nt < 2; ++nt) {
        const int n = wv * 32 + nt * 16 + ln;
        b1q[nt] = *(const float4*)&lb1[wv * 32 + nt * 16 + q * 4];
        b2s[nt] = lb2[n];
        #pragma unroll
        for (int kk = 0; kk < 4; ++kk) {
            #pragma unroll
            for (int j = 0; j < 8; ++j) {
                const int c = kk * 32 + q * 8 + j;
                const int rk = (c < 67) ? c : c - 1;
                w1f[nt][kk][j] = (__bf16)((c == 67) ? 0.0f : lw1[rk * HD + n]);
                w2f[nt][kk][j] = (__bf16)lw2[c * HD + n];
            }
        }
    }

    for (int g = 0; g < GPB; ++g) {
        const int e0 = (blockIdx.x * GPB + g) * 64;

        commit();  // staged x -> ein (waits on prefetch loads)

        // ---- positional encoding (192 threads: e = t&63, d = t>>6) ----
        if (t < 192) {
            const int e = t & 63, d = t >> 6;
            const int r = row[e0 + e];
            const int c = col[e0 + e];
            const int s = idx[r];
            const int esw = e & 7;
            const float pd = pos[c * 3 + d] - pos[s * 3 + d];
            if (d == 0) {
                srow[g & 1][e] = r;
                const float pd1 = pos[c * 3 + 1] - pos[s * 3 + 1];
                const float pd2 = pos[c * 3 + 2] - pos[s * 3 + 2];
                uint2 pkt;
                pkt.x = bf_bits(pd) | (bf_bits(pd1) << 16);
                pkt.y = bf_bits(pd2);  // col 67 = 0
                *(uint2*)&ein[e][(8 ^ esw) * 8] = pkt;
            }
            float rev = pd * 0.5f;  // sin(pd*pi*2^l) = sin(2pi * pd*2^(l-1))
            #pragma unroll
            for (int l = 0; l < 10; ++l) {
                const float fr = __builtin_amdgcn_fractf(rev);
                const float sv = __builtin_amdgcn_sinf(fr);
                const float cv = __builtin_amdgcn_cosf(fr);
                const int colp = 68 + d * 20 + l * 2;
                *(unsigned*)&ein[e][((colp >> 3) ^ esw) * 8 + (colp & 7)] =
                    bf_bits(sv) | (bf_bits(cv) << 16);
                rev *= 2.0f;  // exact
            }
        }

        if (g + 1 < GPB) issue(e0 + 64);  // prefetch next group under the GEMMs

        __syncthreads();  // A: ein/srow ready

        // ---- GEMM1 (swapped): D1[n][e] = W1^T @ ein^T ----
        {
            f32x4 acc[2][4];
            #pragma unroll
            for (int nt = 0; nt < 2; ++nt)
                #pragma unroll
                for (int et = 0; et < 4; ++et)
                    acc[nt][et] = (f32x4){b1q[nt].x, b1q[nt].y, b1q[nt].z, b1q[nt].w};
            #pragma unroll
            for (int et = 0; et < 4; ++et) {
                const int e = et * 16 + ln;
                #pragma unroll
                for (int kk = 0; kk < 4; ++kk) {
                    bf16x8 a = *(const bf16x8*)&ein[e][((kk * 4 + q) ^ lsw) * 8];
                    acc[0][et] = __builtin_amdgcn_mfma_f32_16x16x32_bf16(w1f[0][kk], a, acc[0][et], 0, 0, 0);
                    acc[1][et] = __builtin_amdgcn_mfma_f32_16x16x32_bf16(w1f[1][kk], a, acc[1][et], 0, 0, 0);
                }
            }
            // lane holds h[e=et*16+ln][n = wv*32+nt*16+q*4+r] -> b64 swizzled stores
            #pragma unroll
            for (int et = 0; et < 4; ++et) {
                const int e = et * 16 + ln;
                #pragma unroll
                for (int nt = 0; nt < 2; ++nt) {
                    bf16x4 hv;
                    hv[0] = (__bf16)fmaxf(acc[nt][et][0], 0.0f);
                    hv[1] = (__bf16)fmaxf(acc[nt][et][1], 0.0f);
                    hv[2] = (__bf16)fmaxf(acc[nt][et][2], 0.0f);
                    hv[3] = (__bf16)fmaxf(acc[nt][et][3], 0.0f);
                    const int chunk = wv * 4 + nt * 2 + (q >> 1);
                    *(bf16x4*)&hbuf[e][((chunk ^ lsw) * 8) + (q & 1) * 4] = hv;
                }
            }
        }
        __syncthreads();  // B: hbuf ready; ein free for next commit

        // ---- GEMM2 (non-swapped): D2[e][n]; lane: e = et*16+q*4+r, n = wv*32+nt*16+ln ----
        {
            f32x4 acc[4][2];
            #pragma unroll
            for (int et = 0; et < 4; ++et)
                #pragma unroll
                for (int nt = 0; nt < 2; ++nt)
                    acc[et][nt] = (f32x4){b2s[nt], b2s[nt], b2s[nt], b2s[nt]};
            #pragma unroll
            for (int et = 0; et < 4; ++et) {
                const int e = et * 16 + ln;
                #pragma unroll
                for (int kk = 0; kk < 4; ++kk) {
                    bf16x8 ah = *(const bf16x8*)&hbuf[e][((kk * 4 + q) ^ lsw) * 8];
                    acc[et][0] = __builtin_amdgcn_mfma_f32_16x16x32_bf16(ah, w2f[0][kk], acc[et][0], 0, 0, 0);
                    acc[et][1] = __builtin_amdgcn_mfma_f32_16x16x32_bf16(ah, w2f[1][kk], acc[et][1], 0, 0, 0);
                }
            }

            // ---- sequential segment max over each 4-edge chunk + atomic emits ----
            const int sb = g & 1;
            #pragma unroll
            for (int et = 0; et < 4; ++et) {
                const int4 R = *(const int4*)&srow[sb][et * 16 + q * 4];
                #pragma unroll
                for (int nt = 0; nt < 2; ++nt) {
                    unsigned* base = agg + wv * 32 + nt * 16 + ln;
                    const f32x4 vv = acc[et][nt];
                    int cur = R.x;
                    float m = vv[0];
                    if (R.y != cur) { atomicMax(base + (size_t)cur * HD, enc_f(m)); cur = R.y; m = vv[1]; }
                    else m = fmaxf(m, vv[1]);
                    if (R.z != cur) { atomicMax(base + (size_t)cur * HD, enc_f(m)); cur = R.z; m = vv[2]; }
                    else m = fmaxf(m, vv[2]);
                    if (R.w != cur) { atomicMax(base + (size_t)cur * HD, enc_f(m)); cur = R.w; m = vv[3]; }
                    else m = fmaxf(m, vv[3]);
                    atomicMax(base + (size_t)cur * HD, enc_f(m));  // chunk tail
                }
            }
        }
    }
}

// out = decode(agg) @ gw + gb, empty rows -> 0
__launch_bounds__(256, 4)
__global__ void k_out(const unsigned* __restrict__ agg, const float* __restrict__ gw,
                      const float* __restrict__ gb, float* __restrict__ out) {
    __shared__ float a[32][HD];
    const int t = threadIdx.x;
    const int m0 = blockIdx.x * 32;
    for (int i = t; i < 32 * HD; i += 256) {
        unsigned e = agg[(size_t)m0 * HD + i];
        a[i >> 7][i & 127] = (e == ENC_NEG_INF) ? 0.0f : dec_f(e);
    }
    __syncthreads();
    const int j4 = (t & 63) * 4;
    const int rbase = (t >> 6) * 8;
    float acc[8][4];
    const float4 bias = *(const float4*)&gb[j4];
    #pragma unroll
    for (int r = 0; r < 8; ++r) { acc[r][0] = bias.x; acc[r][1] = bias.y; acc[r][2] = bias.z; acc[r][3] = bias.w; }
    for (int k = 0; k < 128; k += 4) {
        float4 w0 = *(const float4*)&gw[(k + 0) * OD + j4];
        float4 w1 = *(const float4*)&gw[(k + 1) * OD + j4];
        float4 w2 = *(const float4*)&gw[(k + 2) * OD + j4];
        float4 w3 = *(const float4*)&gw[(k + 3) * OD + j4];
        #pragma unroll
        for (int r = 0; r < 8; ++r) {
            float4 av = *(const float4*)&a[rbase + r][k];
            acc[r][0] += av.x * w0.x + av.y * w1.x + av.z * w2.x + av.w * w3.x;
            acc[r][1] += av.x * w0.y + av.y * w1.y + av.z * w2.y + av.w * w3.y;
            acc[r][2] += av.x * w0.z + av.y * w1.z + av.z * w2.z + av.w * w3.z;
            acc[r][3] += av.x * w0.w + av.y * w1.w + av.z * w2.w + av.w * w3.w;
        }
    }
    #pragma unroll
    for (int r = 0; r < 8; ++r) {
        float4 v; v.x = acc[r][0]; v.y = acc[r][1]; v.z = acc[r][2]; v.w = acc[r][3];
        *(float4*)&out[(size_t)(m0 + rbase + r) * OD + j4] = v;
    }
}

extern "C" void kernel_launch(void* const* d_in, const int* in_sizes, int n_in,
                              void* d_out, int out_size, void* d_ws, size_t ws_size,
                              hipStream_t stream) {
    const float* x   = (const float*)d_in[0];
    const float* pos = (const float*)d_in[1];
    const int* batch = (const int*)d_in[2];
    const int* idx   = (const int*)d_in[3];
    const int* row   = (const int*)d_in[4];
    const int* col   = (const int*)d_in[5];
    const float* lw1 = (const float*)d_in[6];
    const float* lb1 = (const float*)d_in[7];
    const float* lw2 = (const float*)d_in[8];
    const float* lb2 = (const float*)d_in[9];
    const float* gw  = (const float*)d_in[10];
    const float* gb  = (const float*)d_in[11];
    float* out = (float*)d_out;
    unsigned* agg = (unsigned*)d_ws;  // MM*HD*4 = 8 MB

    hipLaunchKernelGGL(k_init, dim3((MM * HD + 255) / 256), dim3(256), 0, stream, agg);
    hipLaunchKernelGGL(k_prep, dim3((MM + 255) / 256), dim3(256), 0, stream, pos, batch, idx, out);
    hipLaunchKernelGGL(k_edge, dim3(EE / (64 * GPB)), dim3(256), 0, stream,
                       x, pos, idx, row, col, lw1, lb1, lw2, lb2, agg);
    hipLaunchKernelGGL(k_out, dim3(MM / 32), dim3(256), 0, stream, agg, gw, gb, out);
}

// Round 6
// 153.788 us; speedup vs baseline: 1.6234x; 1.6234x over previous
//
#include <hip/hip_runtime.h>
#include <math.h>

#define NN 65536
#define MM 16384
#define EE 524288
#define CF 64
#define HD 128
#define OD 256
#define GPB 4   // 64-edge groups per block

typedef __bf16 bf16x8 __attribute__((ext_vector_type(8)));
typedef __bf16 bf16x4 __attribute__((ext_vector_type(4)));
typedef float f32x4 __attribute__((ext_vector_type(4)));

__device__ __forceinline__ unsigned enc_f(float f) {
    unsigned u = __float_as_uint(f);
    return (u & 0x80000000u) ? ~u : (u | 0x80000000u);
}
__device__ __forceinline__ float dec_f(unsigned e) {
    unsigned u = (e & 0x80000000u) ? (e ^ 0x80000000u) : ~e;
    return __uint_as_float(u);
}
#define ENC_NEG_INF 0x007FFFFFu
#define AGG_BYTES (MM * HD * 4)  // 8 MB; frag buffer lives after this

__device__ __forceinline__ unsigned bf_bits(float f) {
    __bf16 b = (__bf16)f;
    return (unsigned)__builtin_bit_cast(unsigned short, b);
}

// DPP within 16-lane rows
template <int N>
__device__ __forceinline__ int shup_i(int v) {
    return __builtin_amdgcn_update_dpp(v, v, 0x110 | N, 0xF, 0xF, false);
}
template <int N>
__device__ __forceinline__ float shup_f(float v) {
    return __builtin_bit_cast(float, shup_i<N>(__builtin_bit_cast(int, v)));
}
__device__ __forceinline__ int shdn1_i(int v) {
    return __builtin_amdgcn_update_dpp(v, v, 0x101, 0xF, 0xF, false);
}
template <int OFF>
__device__ __forceinline__ void segstep(int r, int ln, float (&v)[8]) {
    int rn = shup_i<OFF>(r);
    bool ok = (ln >= OFF) && (rn == r);
    #pragma unroll
    for (int i = 0; i < 8; ++i) {
        float vn = shup_f<OFF>(v[i]);
        if (ok) v[i] = fmaxf(v[i], vn);
    }
}

// block 0: build pre-swizzled weight fragments; blocks 1+: init agg.
// frag layout: fragbuf[fi*256 + t] (bf16x8), fi = w2?8:0 + nt*4 + kk, t = thread id in k_edge.
// edge_in column map: [x:0-63][pd:64-66][zero:67][d0 pairs:68-87][d1:88-107][d2:108-127]
__global__ void k_init(unsigned* __restrict__ agg, __bf16* __restrict__ fragbuf,
                       const float* __restrict__ lw1, const float* __restrict__ lw2) {
    if (blockIdx.x == 0) {
        const int t = threadIdx.x;
        const int lane = t & 63;
        const int wv = t >> 6;
        const int q = lane >> 4;
        const int ln = lane & 15;
        #pragma unroll
        for (int fi = 0; fi < 16; ++fi) {
            const int nt = (fi >> 2) & 1, kk = fi & 3;
            const int n = wv * 32 + nt * 16 + ln;
            bf16x8 f;
            #pragma unroll
            for (int j = 0; j < 8; ++j) {
                const int c = kk * 32 + q * 8 + j;
                const int rk = (c < 67) ? c : c - 1;
                f[j] = (fi < 8) ? (__bf16)((c == 67) ? 0.0f : lw1[rk * HD + n])
                                : (__bf16)lw2[c * HD + n];
            }
            *(bf16x8*)&fragbuf[((size_t)fi * 256 + t) * 8] = f;
        }
    } else {
        int i = (blockIdx.x - 1) * 256 + threadIdx.x;
        if (i < MM * HD) agg[i] = ENC_NEG_INF;
    }
}

__global__ void k_prep(const float* __restrict__ pos, const int* __restrict__ batch,
                       const int* __restrict__ idx, float* __restrict__ out) {
    int m = blockIdx.x * 256 + threadIdx.x;
    if (m >= MM) return;
    int s = idx[m];
    out[MM * OD + m * 3 + 0] = pos[s * 3 + 0];
    out[MM * OD + m * 3 + 1] = pos[s * 3 + 1];
    out[MM * OD + m * 3 + 2] = pos[s * 3 + 2];
    out[MM * OD + MM * 3 + m] = (float)batch[s];
}

// Fused edge kernel, software-pipelined:
// phase1(g): GEMM1(ein[p]) -> hbuf  ||  commit+PE(g+1) -> ein[p^1]
// phase2(g): GEMM2(hbuf) -> DPP segmax -> leader atomics
__launch_bounds__(256, 3)
__global__ void k_edge(const float* __restrict__ x, const float* __restrict__ pos,
                       const int* __restrict__ idx, const int* __restrict__ row,
                       const int* __restrict__ col, const __bf16* __restrict__ fragbuf,
                       const float* __restrict__ lb1, const float* __restrict__ lb2,
                       unsigned* __restrict__ agg) {
    __shared__ __align__(16) __bf16 ein[2][64][HD];  // 32 KB, double-buffered
    __shared__ __align__(16) __bf16 hbuf[64][HD];    // 16 KB
    __shared__ int srow[2][64];
    const int t = threadIdx.x;
    const int lane = t & 63;
    const int wv = t >> 6;
    const int q = lane >> 4;
    const int ln = lane & 15;
    const int lsw = ln & 7;
    const int E0 = blockIdx.x * GPB * 64;

    // staging identity: edge pe_e, 16-col slice pe_part
    const int pe_e = t >> 2, pe_part = t & 3, pe_esw = pe_e & 7;
    float4 v0, v1, v2, v3;
    auto issue = [&](int e0) {
        const int c = col[e0 + pe_e];
        const float4* xr = (const float4*)(x + (size_t)c * CF) + pe_part * 4;
        v0 = xr[0]; v1 = xr[1]; v2 = xr[2]; v3 = xr[3];
    };
    auto commit = [&](int b) {
        bf16x8 pk;
        pk[0] = (__bf16)v0.x; pk[1] = (__bf16)v0.y; pk[2] = (__bf16)v0.z; pk[3] = (__bf16)v0.w;
        pk[4] = (__bf16)v1.x; pk[5] = (__bf16)v1.y; pk[6] = (__bf16)v1.z; pk[7] = (__bf16)v1.w;
        *(bf16x8*)&ein[b][pe_e][((pe_part * 2 + 0) ^ pe_esw) * 8] = pk;
        pk[0] = (__bf16)v2.x; pk[1] = (__bf16)v2.y; pk[2] = (__bf16)v2.z; pk[3] = (__bf16)v2.w;
        pk[4] = (__bf16)v3.x; pk[5] = (__bf16)v3.y; pk[6] = (__bf16)v3.z; pk[7] = (__bf16)v3.w;
        *(bf16x8*)&ein[b][pe_e][((pe_part * 2 + 1) ^ pe_esw) * 8] = pk;
    };
    // PE: one fract+sin+cos then 9 double-angle steps (error << bf16 quantum)
    auto do_pe = [&](int g2) {
        if (t < 192) {
            const int e = t & 63, d = t >> 6;
            const int b = g2 & 1;
            const int e0b = E0 + g2 * 64;
            const int r = row[e0b + e];
            const int c = col[e0b + e];
            const int s = idx[r];
            const int esw = e & 7;
            const float pd = pos[c * 3 + d] - pos[s * 3 + d];
            if (d == 0) {
                srow[b][e] = r;
                const float pd1 = pos[c * 3 + 1] - pos[s * 3 + 1];
                const float pd2 = pos[c * 3 + 2] - pos[s * 3 + 2];
                uint2 pkt;
                pkt.x = bf_bits(pd) | (bf_bits(pd1) << 16);
                pkt.y = bf_bits(pd2);  // col 67 = 0
                *(uint2*)&ein[b][e][(8 ^ esw) * 8] = pkt;
            }
            const float fr = __builtin_amdgcn_fractf(pd * 0.5f);
            float sv = __builtin_amdgcn_sinf(fr);
            float cv = __builtin_amdgcn_cosf(fr);
            #pragma unroll
            for (int l = 0; l < 10; ++l) {
                const int colp = 68 + d * 20 + l * 2;
                *(unsigned*)&ein[b][e][((colp >> 3) ^ esw) * 8 + (colp & 7)] =
                    bf_bits(sv) | (bf_bits(cv) << 16);
                const float s2 = 2.0f * sv * cv;
                const float c2 = 1.0f - 2.0f * sv * sv;
                sv = s2; cv = c2;
            }
        }
    };

    issue(E0);  // longest-latency first

    // weight fragments: 16 coalesced b128 loads
    bf16x8 w1f[2][4], w2f[2][4];
    #pragma unroll
    for (int nt = 0; nt < 2; ++nt)
        #pragma unroll
        for (int kk = 0; kk < 4; ++kk) {
            w1f[nt][kk] = *(const bf16x8*)&fragbuf[((size_t)(nt * 4 + kk) * 256 + t) * 8];
            w2f[nt][kk] = *(const bf16x8*)&fragbuf[((size_t)(8 + nt * 4 + kk) * 256 + t) * 8];
        }
    float4 b1q[2], b2q[2];
    #pragma unroll
    for (int nt = 0; nt < 2; ++nt) {
        b1q[nt] = *(const float4*)&lb1[wv * 32 + nt * 16 + q * 4];
        b2q[nt] = *(const float4*)&lb2[wv * 32 + nt * 16 + q * 4];
    }

    commit(0);
    do_pe(0);
    if (GPB > 1) issue(E0 + 64);
    __syncthreads();  // ein[0]/srow[0] ready

    for (int g = 0; g < GPB; ++g) {
        const int p = g & 1;

        // ---- phase1: GEMM1 (swapped, W1 as A): D1[n][e] ----
        f32x4 acc[2][4];
        #pragma unroll
        for (int nt = 0; nt < 2; ++nt)
            #pragma unroll
            for (int et = 0; et < 4; ++et)
                acc[nt][et] = (f32x4){b1q[nt].x, b1q[nt].y, b1q[nt].z, b1q[nt].w};
        #pragma unroll
        for (int et = 0; et < 4; ++et) {
            const int e = et * 16 + ln;
            #pragma unroll
            for (int kk = 0; kk < 4; ++kk) {
                bf16x8 a = *(const bf16x8*)&ein[p][e][((kk * 4 + q) ^ lsw) * 8];
                acc[0][et] = __builtin_amdgcn_mfma_f32_16x16x32_bf16(w1f[0][kk], a, acc[0][et], 0, 0, 0);
                acc[1][et] = __builtin_amdgcn_mfma_f32_16x16x32_bf16(w1f[1][kk], a, acc[1][et], 0, 0, 0);
            }
        }
        // overlapped: stage + PE for next group into the other buffer
        if (g + 1 < GPB) { commit(p ^ 1); do_pe(g + 1); }
        if (g + 2 < GPB) issue(E0 + (g + 2) * 64);
        // relu + b64 swizzled stores: lane holds h[e][n = wv*32+nt*16+q*4+r]
        #pragma unroll
        for (int et = 0; et < 4; ++et) {
            const int e = et * 16 + ln;
            #pragma unroll
            for (int nt = 0; nt < 2; ++nt) {
                bf16x4 hv;
                hv[0] = (__bf16)fmaxf(acc[nt][et][0], 0.0f);
                hv[1] = (__bf16)fmaxf(acc[nt][et][1], 0.0f);
                hv[2] = (__bf16)fmaxf(acc[nt][et][2], 0.0f);
                hv[3] = (__bf16)fmaxf(acc[nt][et][3], 0.0f);
                const int chunk = wv * 4 + nt * 2 + (q >> 1);
                *(bf16x4*)&hbuf[e][((chunk ^ lsw) * 8) + (q & 1) * 4] = hv;
            }
        }
        __syncthreads();  // hbuf ready; ein[p^1] ready for next iter

        // ---- phase2: GEMM2 (swapped, W2 as A): D2[n][e] ----
        f32x4 acc2[2][4];
        #pragma unroll
        for (int nt = 0; nt < 2; ++nt)
            #pragma unroll
            for (int et = 0; et < 4; ++et)
                acc2[nt][et] = (f32x4){b2q[nt].x, b2q[nt].y, b2q[nt].z, b2q[nt].w};
        #pragma unroll
        for (int et = 0; et < 4; ++et) {
            const int e = et * 16 + ln;
            #pragma unroll
            for (int kk = 0; kk < 4; ++kk) {
                bf16x8 a = *(const bf16x8*)&hbuf[e][((kk * 4 + q) ^ lsw) * 8];
                acc2[0][et] = __builtin_amdgcn_mfma_f32_16x16x32_bf16(w2f[0][kk], a, acc2[0][et], 0, 0, 0);
                acc2[1][et] = __builtin_amdgcn_mfma_f32_16x16x32_bf16(w2f[1][kk], a, acc2[1][et], 0, 0, 0);
            }
        }
        // ---- DPP segmented max over 16 edge-lanes + leader atomics (R3-proven) ----
        {
            const int sb = g & 1;
            #pragma unroll
            for (int et = 0; et < 4; ++et) {
                const int e = et * 16 + ln;
                int r = srow[sb][e];
                float v[8];
                #pragma unroll
                for (int i = 0; i < 4; ++i) { v[i] = acc2[0][et][i]; v[4 + i] = acc2[1][et][i]; }
                segstep<1>(r, ln, v);
                segstep<2>(r, ln, v);
                segstep<4>(r, ln, v);
                segstep<8>(r, ln, v);
                const int rnext = shdn1_i(r);
                const bool leader = (ln == 15) || (rnext != r);
                if (leader) {
                    #pragma unroll
                    for (int nt = 0; nt < 2; ++nt)
                        #pragma unroll
                        for (int rr = 0; rr < 4; ++rr)
                            atomicMax(&agg[(size_t)r * HD + wv * 32 + nt * 16 + q * 4 + rr],
                                      enc_f(v[nt * 4 + rr]));
                }
            }
        }
        if (g + 1 < GPB) __syncthreads();  // hbuf free for next GEMM1
    }
}

// out = decode(agg) @ gw + gb, empty rows -> 0
__launch_bounds__(256, 4)
__global__ void k_out(const unsigned* __restrict__ agg, const float* __restrict__ gw,
                      const float* __restrict__ gb, float* __restrict__ out) {
    __shared__ float a[32][HD];
    const int t = threadIdx.x;
    const int m0 = blockIdx.x * 32;
    for (int i = t; i < 32 * HD; i += 256) {
        unsigned e = agg[(size_t)m0 * HD + i];
        a[i >> 7][i & 127] = (e == ENC_NEG_INF) ? 0.0f : dec_f(e);
    }
    __syncthreads();
    const int j4 = (t & 63) * 4;
    const int rbase = (t >> 6) * 8;
    float acc[8][4];
    const float4 bias = *(const float4*)&gb[j4];
    #pragma unroll
    for (int r = 0; r < 8; ++r) { acc[r][0] = bias.x; acc[r][1] = bias.y; acc[r][2] = bias.z; acc[r][3] = bias.w; }
    for (int k = 0; k < 128; k += 4) {
        float4 w0 = *(const float4*)&gw[(k + 0) * OD + j4];
        float4 w1 = *(const float4*)&gw[(k + 1) * OD + j4];
        float4 w2 = *(const float4*)&gw[(k + 2) * OD + j4];
        float4 w3 = *(const float4*)&gw[(k + 3) * OD + j4];
        #pragma unroll
        for (int r = 0; r < 8; ++r) {
            float4 av = *(const float4*)&a[rbase + r][k];
            acc[r][0] += av.x * w0.x + av.y * w1.x + av.z * w2.x + av.w * w3.x;
            acc[r][1] += av.x * w0.y + av.y * w1.y + av.z * w2.y + av.w * w3.y;
            acc[r][2] += av.x * w0.z + av.y * w1.z + av.z * w2.z + av.w * w3.z;
            acc[r][3] += av.x * w0.w + av.y * w1.w + av.z * w2.w + av.w * w3.w;
        }
    }
    #pragma unroll
    for (int r = 0; r < 8; ++r) {
        float4 v; v.x = acc[r][0]; v.y = acc[r][1]; v.z = acc[r][2]; v.w = acc[r][3];
        *(float4*)&out[(size_t)(m0 + rbase + r) * OD + j4] = v;
    }
}

extern "C" void kernel_launch(void* const* d_in, const int* in_sizes, int n_in,
                              void* d_out, int out_size, void* d_ws, size_t ws_size,
                              hipStream_t stream) {
    const float* x   = (const float*)d_in[0];
    const float* pos = (const float*)d_in[1];
    const int* batch = (const int*)d_in[2];
    const int* idx   = (const int*)d_in[3];
    const int* row   = (const int*)d_in[4];
    const int* col   = (const int*)d_in[5];
    const float* lw1 = (const float*)d_in[6];
    const float* lb1 = (const float*)d_in[7];
    const float* lw2 = (const float*)d_in[8];
    const float* lb2 = (const float*)d_in[9];
    const float* gw  = (const float*)d_in[10];
    const float* gb  = (const float*)d_in[11];
    float* out = (float*)d_out;
    unsigned* agg = (unsigned*)d_ws;                                  // 8 MB
    __bf16* fragbuf = (__bf16*)((char*)d_ws + AGG_BYTES);             // 64 KB

    hipLaunchKernelGGL(k_init, dim3((MM * HD + 255) / 256 + 1), dim3(256), 0, stream,
                       agg, fragbuf, lw1, lw2);
    hipLaunchKernelGGL(k_prep, dim3((MM + 255) / 256), dim3(256), 0, stream, pos, batch, idx, out);
    hipLaunchKernelGGL(k_edge, dim3(EE / (64 * GPB)), dim3(256), 0, stream,
                       x, pos, idx, row, col, fragbuf, lb1, lb2, agg);
    hipLaunchKernelGGL(k_out, dim3(MM / 32), dim3(256), 0, stream, agg, gw, gb, out);
}

// Round 7
// 147.936 us; speedup vs baseline: 1.6876x; 1.0396x over previous
//
#include <hip/hip_runtime.h>
#include <math.h>

#define NN 65536
#define MM 16384
#define EE 524288
#define CF 64
#define HD 128
#define OD 256
#define GPB 4   // 64-edge groups per block

typedef __bf16 bf16x8 __attribute__((ext_vector_type(8)));
typedef __bf16 bf16x4 __attribute__((ext_vector_type(4)));
typedef float f32x4 __attribute__((ext_vector_type(4)));

__device__ __forceinline__ unsigned enc_f(float f) {
    unsigned u = __float_as_uint(f);
    return (u & 0x80000000u) ? ~u : (u | 0x80000000u);
}
__device__ __forceinline__ float dec_f(unsigned e) {
    unsigned u = (e & 0x80000000u) ? (e ^ 0x80000000u) : ~e;
    return __uint_as_float(u);
}
#define ENC_NEG_INF 0x007FFFFFu
#define AGG_BYTES (MM * HD * 4)  // 8 MB; frag buffer lives after this

__device__ __forceinline__ unsigned bf_bits(float f) {
    __bf16 b = (__bf16)f;
    return (unsigned)__builtin_bit_cast(unsigned short, b);
}

// DPP within 16-lane rows
template <int N>
__device__ __forceinline__ int shup_i(int v) {
    return __builtin_amdgcn_update_dpp(v, v, 0x110 | N, 0xF, 0xF, false);
}
template <int N>
__device__ __forceinline__ float shup_f(float v) {
    return __builtin_bit_cast(float, shup_i<N>(__builtin_bit_cast(int, v)));
}
__device__ __forceinline__ int shdn1_i(int v) {
    return __builtin_amdgcn_update_dpp(v, v, 0x101, 0xF, 0xF, false);
}
template <int OFF>
__device__ __forceinline__ void segstep(int r, int ln, float (&v)[8]) {
    int rn = shup_i<OFF>(r);
    bool ok = (ln >= OFF) && (rn == r);
    #pragma unroll
    for (int i = 0; i < 8; ++i) {
        float vn = shup_f<OFF>(v[i]);
        if (ok) v[i] = fmaxf(v[i], vn);
    }
}

// block 0: build pre-swizzled weight fragments; blocks 1+: init agg.
// frag layout: fragbuf[fi*256 + t] (bf16x8), fi = w2?8:0 + nt*4 + kk, t = thread id in k_edge.
// edge_in column map: [x:0-63][pd:64-66][zero:67][d0 pairs:68-87][d1:88-107][d2:108-127]
__global__ void k_init(unsigned* __restrict__ agg, __bf16* __restrict__ fragbuf,
                       const float* __restrict__ lw1, const float* __restrict__ lw2) {
    if (blockIdx.x == 0) {
        const int t = threadIdx.x;
        const int lane = t & 63;
        const int wv = t >> 6;
        const int q = lane >> 4;
        const int ln = lane & 15;
        #pragma unroll
        for (int fi = 0; fi < 16; ++fi) {
            const int nt = (fi >> 2) & 1, kk = fi & 3;
            const int n = wv * 32 + nt * 16 + ln;
            bf16x8 f;
            #pragma unroll
            for (int j = 0; j < 8; ++j) {
                const int c = kk * 32 + q * 8 + j;
                const int rk = (c < 67) ? c : c - 1;
                f[j] = (fi < 8) ? (__bf16)((c == 67) ? 0.0f : lw1[rk * HD + n])
                                : (__bf16)lw2[c * HD + n];
            }
            *(bf16x8*)&fragbuf[((size_t)fi * 256 + t) * 8] = f;
        }
    } else {
        int i = (blockIdx.x - 1) * 256 + threadIdx.x;
        if (i < MM * HD) agg[i] = ENC_NEG_INF;
    }
}

__global__ void k_prep(const float* __restrict__ pos, const int* __restrict__ batch,
                       const int* __restrict__ idx, float* __restrict__ out) {
    int m = blockIdx.x * 256 + threadIdx.x;
    if (m >= MM) return;
    int s = idx[m];
    out[MM * OD + m * 3 + 0] = pos[s * 3 + 0];
    out[MM * OD + m * 3 + 1] = pos[s * 3 + 1];
    out[MM * OD + m * 3 + 2] = pos[s * 3 + 2];
    out[MM * OD + MM * 3 + m] = (float)batch[s];
}

// Fused edge kernel, software-pipelined:
// phase1(g): GEMM1(ein[p]) -> hbuf  ||  commit+PE(g+1) -> ein[p^1]
// phase2(g): load w2f JIT, GEMM2(hbuf) -> DPP segmax -> leader atomics
__launch_bounds__(256)
__global__ void k_edge(const float* __restrict__ x, const float* __restrict__ pos,
                       const int* __restrict__ idx, const int* __restrict__ row,
                       const int* __restrict__ col, const __bf16* __restrict__ fragbuf,
                       const float* __restrict__ lb1, const float* __restrict__ lb2,
                       unsigned* __restrict__ agg) {
    __shared__ __align__(16) __bf16 ein[2][64][HD];  // 32 KB, double-buffered
    __shared__ __align__(16) __bf16 hbuf[64][HD];    // 16 KB
    __shared__ int srow[2][64];
    const int t = threadIdx.x;
    const int lane = t & 63;
    const int wv = t >> 6;
    const int q = lane >> 4;
    const int ln = lane & 15;
    const int lsw = ln & 7;
    const int E0 = blockIdx.x * GPB * 64;

    // staging identity: edge pe_e, 16-col slice pe_part
    const int pe_e = t >> 2, pe_part = t & 3, pe_esw = pe_e & 7;
    float4 v0, v1, v2, v3;
    auto issue = [&](int e0) {
        const int c = col[e0 + pe_e];
        const float4* xr = (const float4*)(x + (size_t)c * CF) + pe_part * 4;
        v0 = xr[0]; v1 = xr[1]; v2 = xr[2]; v3 = xr[3];
    };
    auto commit = [&](int b) {
        bf16x8 pk;
        pk[0] = (__bf16)v0.x; pk[1] = (__bf16)v0.y; pk[2] = (__bf16)v0.z; pk[3] = (__bf16)v0.w;
        pk[4] = (__bf16)v1.x; pk[5] = (__bf16)v1.y; pk[6] = (__bf16)v1.z; pk[7] = (__bf16)v1.w;
        *(bf16x8*)&ein[b][pe_e][((pe_part * 2 + 0) ^ pe_esw) * 8] = pk;
        pk[0] = (__bf16)v2.x; pk[1] = (__bf16)v2.y; pk[2] = (__bf16)v2.z; pk[3] = (__bf16)v2.w;
        pk[4] = (__bf16)v3.x; pk[5] = (__bf16)v3.y; pk[6] = (__bf16)v3.z; pk[7] = (__bf16)v3.w;
        *(bf16x8*)&ein[b][pe_e][((pe_part * 2 + 1) ^ pe_esw) * 8] = pk;
    };
    // PE: one fract+sin+cos then 9 double-angle steps (error << bf16 quantum)
    auto do_pe = [&](int g2) {
        if (t < 192) {
            const int e = t & 63, d = t >> 6;
            const int b = g2 & 1;
            const int e0b = E0 + g2 * 64;
            const int r = row[e0b + e];
            const int c = col[e0b + e];
            const int s = idx[r];
            const int esw = e & 7;
            const float pd = pos[c * 3 + d] - pos[s * 3 + d];
            if (d == 0) {
                srow[b][e] = r;
                const float pd1 = pos[c * 3 + 1] - pos[s * 3 + 1];
                const float pd2 = pos[c * 3 + 2] - pos[s * 3 + 2];
                uint2 pkt;
                pkt.x = bf_bits(pd) | (bf_bits(pd1) << 16);
                pkt.y = bf_bits(pd2);  // col 67 = 0
                *(uint2*)&ein[b][e][(8 ^ esw) * 8] = pkt;
            }
            const float fr = __builtin_amdgcn_fractf(pd * 0.5f);
            float sv = __builtin_amdgcn_sinf(fr);
            float cv = __builtin_amdgcn_cosf(fr);
            #pragma unroll
            for (int l = 0; l < 10; ++l) {
                const int colp = 68 + d * 20 + l * 2;
                *(unsigned*)&ein[b][e][((colp >> 3) ^ esw) * 8 + (colp & 7)] =
                    bf_bits(sv) | (bf_bits(cv) << 16);
                const float s2 = 2.0f * sv * cv;
                const float c2 = 1.0f - 2.0f * sv * sv;
                sv = s2; cv = c2;
            }
        }
    };

    issue(E0);  // longest-latency first

    // GEMM1 weight fragments resident; GEMM2 frags loaded JIT in phase2
    bf16x8 w1f[2][4];
    #pragma unroll
    for (int nt = 0; nt < 2; ++nt)
        #pragma unroll
        for (int kk = 0; kk < 4; ++kk)
            w1f[nt][kk] = *(const bf16x8*)&fragbuf[((size_t)(nt * 4 + kk) * 256 + t) * 8];
    float4 b1q[2];
    #pragma unroll
    for (int nt = 0; nt < 2; ++nt)
        b1q[nt] = *(const float4*)&lb1[wv * 32 + nt * 16 + q * 4];

    commit(0);
    do_pe(0);
    if (GPB > 1) issue(E0 + 64);
    __syncthreads();  // ein[0]/srow[0] ready

    for (int g = 0; g < GPB; ++g) {
        const int p = g & 1;

        // ---- phase1: GEMM1 (swapped, W1 as A): D1[n][e] ----
        f32x4 acc[2][4];
        #pragma unroll
        for (int nt = 0; nt < 2; ++nt)
            #pragma unroll
            for (int et = 0; et < 4; ++et)
                acc[nt][et] = (f32x4){b1q[nt].x, b1q[nt].y, b1q[nt].z, b1q[nt].w};
        #pragma unroll
        for (int et = 0; et < 4; ++et) {
            const int e = et * 16 + ln;
            #pragma unroll
            for (int kk = 0; kk < 4; ++kk) {
                bf16x8 a = *(const bf16x8*)&ein[p][e][((kk * 4 + q) ^ lsw) * 8];
                acc[0][et] = __builtin_amdgcn_mfma_f32_16x16x32_bf16(w1f[0][kk], a, acc[0][et], 0, 0, 0);
                acc[1][et] = __builtin_amdgcn_mfma_f32_16x16x32_bf16(w1f[1][kk], a, acc[1][et], 0, 0, 0);
            }
        }
        // overlapped: stage + PE for next group into the other buffer
        if (g + 1 < GPB) { commit(p ^ 1); do_pe(g + 1); }
        if (g + 2 < GPB) issue(E0 + (g + 2) * 64);
        // relu + b64 swizzled stores: lane holds h[e][n = wv*32+nt*16+q*4+r]
        #pragma unroll
        for (int et = 0; et < 4; ++et) {
            const int e = et * 16 + ln;
            #pragma unroll
            for (int nt = 0; nt < 2; ++nt) {
                bf16x4 hv;
                hv[0] = (__bf16)fmaxf(acc[nt][et][0], 0.0f);
                hv[1] = (__bf16)fmaxf(acc[nt][et][1], 0.0f);
                hv[2] = (__bf16)fmaxf(acc[nt][et][2], 0.0f);
                hv[3] = (__bf16)fmaxf(acc[nt][et][3], 0.0f);
                const int chunk = wv * 4 + nt * 2 + (q >> 1);
                *(bf16x4*)&hbuf[e][((chunk ^ lsw) * 8) + (q & 1) * 4] = hv;
            }
        }
        __syncthreads();  // hbuf ready; ein[p^1] ready for next iter

        // ---- phase2: load w2f JIT (L1/L2-hit), GEMM2 (swapped, W2 as A): D2[n][e] ----
        {
            bf16x8 w2f[2][4];
            #pragma unroll
            for (int nt = 0; nt < 2; ++nt)
                #pragma unroll
                for (int kk = 0; kk < 4; ++kk)
                    w2f[nt][kk] = *(const bf16x8*)&fragbuf[((size_t)(8 + nt * 4 + kk) * 256 + t) * 8];

            f32x4 acc2[2][4];
            #pragma unroll
            for (int nt = 0; nt < 2; ++nt) {
                const float4 b2q = *(const float4*)&lb2[wv * 32 + nt * 16 + q * 4];
                #pragma unroll
                for (int et = 0; et < 4; ++et)
                    acc2[nt][et] = (f32x4){b2q.x, b2q.y, b2q.z, b2q.w};
            }
            #pragma unroll
            for (int et = 0; et < 4; ++et) {
                const int e = et * 16 + ln;
                #pragma unroll
                for (int kk = 0; kk < 4; ++kk) {
                    bf16x8 a = *(const bf16x8*)&hbuf[e][((kk * 4 + q) ^ lsw) * 8];
                    acc2[0][et] = __builtin_amdgcn_mfma_f32_16x16x32_bf16(w2f[0][kk], a, acc2[0][et], 0, 0, 0);
                    acc2[1][et] = __builtin_amdgcn_mfma_f32_16x16x32_bf16(w2f[1][kk], a, acc2[1][et], 0, 0, 0);
                }
            }
            // ---- DPP segmented max over 16 edge-lanes + leader atomics ----
            const int sb = g & 1;
            #pragma unroll
            for (int et = 0; et < 4; ++et) {
                const int e = et * 16 + ln;
                int r = srow[sb][e];
                float v[8];
                #pragma unroll
                for (int i = 0; i < 4; ++i) { v[i] = acc2[0][et][i]; v[4 + i] = acc2[1][et][i]; }
                segstep<1>(r, ln, v);
                segstep<2>(r, ln, v);
                segstep<4>(r, ln, v);
                segstep<8>(r, ln, v);
                const int rnext = shdn1_i(r);
                const bool leader = (ln == 15) || (rnext != r);
                if (leader) {
                    #pragma unroll
                    for (int nt = 0; nt < 2; ++nt)
                        #pragma unroll
                        for (int rr = 0; rr < 4; ++rr)
                            atomicMax(&agg[(size_t)r * HD + wv * 32 + nt * 16 + q * 4 + rr],
                                      enc_f(v[nt * 4 + rr]));
                }
            }
        }
        if (g + 1 < GPB) __syncthreads();  // hbuf free for next GEMM1
    }
}

// out = decode(agg) @ gw + gb, empty rows -> 0
__launch_bounds__(256, 4)
__global__ void k_out(const unsigned* __restrict__ agg, const float* __restrict__ gw,
                      const float* __restrict__ gb, float* __restrict__ out) {
    __shared__ float a[32][HD];
    const int t = threadIdx.x;
    const int m0 = blockIdx.x * 32;
    for (int i = t; i < 32 * HD; i += 256) {
        unsigned e = agg[(size_t)m0 * HD + i];
        a[i >> 7][i & 127] = (e == ENC_NEG_INF) ? 0.0f : dec_f(e);
    }
    __syncthreads();
    const int j4 = (t & 63) * 4;
    const int rbase = (t >> 6) * 8;
    float acc[8][4];
    const float4 bias = *(const float4*)&gb[j4];
    #pragma unroll
    for (int r = 0; r < 8; ++r) { acc[r][0] = bias.x; acc[r][1] = bias.y; acc[r][2] = bias.z; acc[r][3] = bias.w; }
    for (int k = 0; k < 128; k += 4) {
        float4 w0 = *(const float4*)&gw[(k + 0) * OD + j4];
        float4 w1 = *(const float4*)&gw[(k + 1) * OD + j4];
        float4 w2 = *(const float4*)&gw[(k + 2) * OD + j4];
        float4 w3 = *(const float4*)&gw[(k + 3) * OD + j4];
        #pragma unroll
        for (int r = 0; r < 8; ++r) {
            float4 av = *(const float4*)&a[rbase + r][k];
            acc[r][0] += av.x * w0.x + av.y * w1.x + av.z * w2.x + av.w * w3.x;
            acc[r][1] += av.x * w0.y + av.y * w1.y + av.z * w2.y + av.w * w3.y;
            acc[r][2] += av.x * w0.z + av.y * w1.z + av.z * w2.z + av.w * w3.z;
            acc[r][3] += av.x * w0.w + av.y * w1.w + av.z * w2.w + av.w * w3.w;
        }
    }
    #pragma unroll
    for (int r = 0; r < 8; ++r) {
        float4 v; v.x = acc[r][0]; v.y = acc[r][1]; v.z = acc[r][2]; v.w = acc[r][3];
        *(float4*)&out[(size_t)(m0 + rbase + r) * OD + j4] = v;
    }
}

extern "C" void kernel_launch(void* const* d_in, const int* in_sizes, int n_in,
                              void* d_out, int out_size, void* d_ws, size_t ws_size,
                              hipStream_t stream) {
    const float* x   = (const float*)d_in[0];
    const float* pos = (const float*)d_in[1];
    const int* batch = (const int*)d_in[2];
    const int* idx   = (const int*)d_in[3];
    const int* row   = (const int*)d_in[4];
    const int* col   = (const int*)d_in[5];
    const float* lw1 = (const float*)d_in[6];
    const float* lb1 = (const float*)d_in[7];
    const float* lw2 = (const float*)d_in[8];
    const float* lb2 = (const float*)d_in[9];
    const float* gw  = (const float*)d_in[10];
    const float* gb  = (const float*)d_in[11];
    float* out = (float*)d_out;
    unsigned* agg = (unsigned*)d_ws;                                  // 8 MB
    __bf16* fragbuf = (__bf16*)((char*)d_ws + AGG_BYTES);             // 64 KB

    hipLaunchKernelGGL(k_init, dim3((MM * HD + 255) / 256 + 1), dim3(256), 0, stream,
                       agg, fragbuf, lw1, lw2);
    hipLaunchKernelGGL(k_prep, dim3((MM + 255) / 256), dim3(256), 0, stream, pos, batch, idx, out);
    hipLaunchKernelGGL(k_edge, dim3(EE / (64 * GPB)), dim3(256), 0, stream,
                       x, pos, idx, row, col, fragbuf, lb1, lb2, agg);
    hipLaunchKernelGGL(k_out, dim3(MM / 32), dim3(256), 0, stream, agg, gw, gb, out);
}

// Round 8
// 117.119 us; speedup vs baseline: 2.1316x; 1.2631x over previous
//
#include <hip/hip_runtime.h>
#include <math.h>

#define NN 65536
#define MM 16384
#define EE 524288
#define CF 64
#define HD 128
#define OD 256
#define RPB 16        // output rows per block
#define PITCH 129     // maxbuf row pitch (de-banked)

typedef __bf16 bf16x8 __attribute__((ext_vector_type(8)));
typedef __bf16 bf16x4 __attribute__((ext_vector_type(4)));
typedef float f32x4 __attribute__((ext_vector_type(4)));

__device__ __forceinline__ unsigned enc_f(float f) {
    unsigned u = __float_as_uint(f);
    return (u & 0x80000000u) ? ~u : (u | 0x80000000u);
}
__device__ __forceinline__ float dec_f(unsigned e) {
    unsigned u = (e & 0x80000000u) ? (e ^ 0x80000000u) : ~e;
    return __uint_as_float(u);
}
#define ENC_NEG_INF 0x007FFFFFu

__device__ __forceinline__ unsigned bf_bits(float f) {
    __bf16 b = (__bf16)f;
    return (unsigned)__builtin_bit_cast(unsigned short, b);
}

// build pre-swizzled weight fragments (1 block).
// fragbuf[fi*256 + t] (bf16x8): fi = (w2?8:0) + nt*4 + kk; element j = W[c][n],
// c = kk*32+q*8+j, n = wv*32+nt*16+ln. Column map (K permuted, weights permuted to match):
// [x:0-63][pd:64-66][zero:67][d0 pairs:68-87][d1:88-107][d2:108-127]
__global__ void k_wprep(__bf16* __restrict__ fragbuf,
                        const float* __restrict__ lw1, const float* __restrict__ lw2) {
    const int t = threadIdx.x;
    const int lane = t & 63;
    const int wv = t >> 6;
    const int q = lane >> 4;
    const int ln = lane & 15;
    #pragma unroll
    for (int fi = 0; fi < 16; ++fi) {
        const int nt = (fi >> 2) & 1, kk = fi & 3;
        const int n = wv * 32 + nt * 16 + ln;
        bf16x8 f;
        #pragma unroll
        for (int j = 0; j < 8; ++j) {
            const int c = kk * 32 + q * 8 + j;
            const int rk = (c < 67) ? c : c - 1;
            f[j] = (fi < 8) ? (__bf16)((c == 67) ? 0.0f : lw1[rk * HD + n])
                            : (__bf16)lw2[c * HD + n];
        }
        *(bf16x8*)&fragbuf[((size_t)fi * 256 + t) * 8] = f;
    }
}

__global__ void k_prep(const float* __restrict__ pos, const int* __restrict__ batch,
                       const int* __restrict__ idx, float* __restrict__ out) {
    int m = blockIdx.x * 256 + threadIdx.x;
    if (m >= MM) return;
    int s = idx[m];
    out[MM * OD + m * 3 + 0] = pos[s * 3 + 0];
    out[MM * OD + m * 3 + 1] = pos[s * 3 + 1];
    out[MM * OD + m * 3 + 2] = pos[s * 3 + 2];
    out[MM * OD + MM * 3 + m] = (float)batch[s];
}

// Fully fused: block owns rows [m0, m0+16), edges [es, ee) (contiguous, row sorted).
// phase1(tt): GEMM1(ein[p]) -> hbuf  ||  commit+PE(tt+1) -> ein[p^1]
// phase2(tt): w2f JIT, GEMM2 non-swapped -> run-compress -> ds_max into maxbuf
// epilogue: decode maxbuf -> final 128->256 GEMM -> out
__launch_bounds__(256)
__global__ void k_fused(const float* __restrict__ x, const float* __restrict__ pos,
                        const int* __restrict__ idx, const int* __restrict__ row,
                        const int* __restrict__ col, const __bf16* __restrict__ fragbuf,
                        const float* __restrict__ lb1, const float* __restrict__ lb2,
                        const float* __restrict__ gw, const float* __restrict__ gb,
                        float* __restrict__ out) {
    __shared__ __align__(16) __bf16 ein[2][64][HD];        // 32 KB
    __shared__ __align__(16) __bf16 hbuf[64][HD];          // 16 KB (reused as afin f32[16][128])
    __shared__ unsigned maxbuf[(RPB + 1) * PITCH];         // 8.6 KB
    __shared__ int srow[2][64];
    const int t = threadIdx.x;
    const int lane = t & 63;
    const int wv = t >> 6;
    const int q = lane >> 4;
    const int ln = lane & 15;
    const int lsw = ln & 7;
    const int m0 = blockIdx.x * RPB;

    // edge range for this block's rows (every thread computes; row[] is sorted)
    auto lbound = [&](int target) {
        int lo = 0, hi = EE;
        while (lo < hi) { int mid = (lo + hi) >> 1; if (row[mid] < target) lo = mid + 1; else hi = mid; }
        return lo;
    };
    const int es = lbound(m0);
    const int ee = lbound(m0 + RPB);
    const int ntiles = (ee - es + 63) >> 6;

    // init maxbuf
    for (int i = t; i < (RPB + 1) * PITCH; i += 256) maxbuf[i] = ENC_NEG_INF;

    // staging identity: edge pe_e, 16-col slice pe_part
    const int pe_e = t >> 2, pe_part = t & 3, pe_esw = pe_e & 7;
    float4 v0, v1, v2, v3;
    auto issue = [&](int tt) {
        const int eg = min(es + tt * 64 + pe_e, EE - 1);
        const int c = col[eg];
        const float4* xr = (const float4*)(x + (size_t)c * CF) + pe_part * 4;
        v0 = xr[0]; v1 = xr[1]; v2 = xr[2]; v3 = xr[3];
    };
    auto commit = [&](int b) {
        bf16x8 pk;
        pk[0] = (__bf16)v0.x; pk[1] = (__bf16)v0.y; pk[2] = (__bf16)v0.z; pk[3] = (__bf16)v0.w;
        pk[4] = (__bf16)v1.x; pk[5] = (__bf16)v1.y; pk[6] = (__bf16)v1.z; pk[7] = (__bf16)v1.w;
        *(bf16x8*)&ein[b][pe_e][((pe_part * 2 + 0) ^ pe_esw) * 8] = pk;
        pk[0] = (__bf16)v2.x; pk[1] = (__bf16)v2.y; pk[2] = (__bf16)v2.z; pk[3] = (__bf16)v2.w;
        pk[4] = (__bf16)v3.x; pk[5] = (__bf16)v3.y; pk[6] = (__bf16)v3.z; pk[7] = (__bf16)v3.w;
        *(bf16x8*)&ein[b][pe_e][((pe_part * 2 + 1) ^ pe_esw) * 8] = pk;
    };
    auto do_pe = [&](int tt) {
        if (t < 192) {
            const int e = t & 63, d = t >> 6;
            const int b = tt & 1;
            const int eidx = es + tt * 64 + e;
            const int eg = min(eidx, EE - 1);
            const int r = row[eg];
            const int c = col[eg];
            const int s = idx[r];
            const int esw = e & 7;
            const float pd = pos[c * 3 + d] - pos[s * 3 + d];
            if (d == 0) {
                srow[b][e] = (eidx < ee) ? (r - m0) : RPB;  // dummy row for tails
                const float pd1 = pos[c * 3 + 1] - pos[s * 3 + 1];
                const float pd2 = pos[c * 3 + 2] - pos[s * 3 + 2];
                uint2 pkt;
                pkt.x = bf_bits(pd) | (bf_bits(pd1) << 16);
                pkt.y = bf_bits(pd2);  // col 67 = 0
                *(uint2*)&ein[b][e][(8 ^ esw) * 8] = pkt;
            }
            const float fr = __builtin_amdgcn_fractf(pd * 0.5f);
            float sv = __builtin_amdgcn_sinf(fr);
            float cv = __builtin_amdgcn_cosf(fr);
            #pragma unroll
            for (int l = 0; l < 10; ++l) {
                const int colp = 68 + d * 20 + l * 2;
                *(unsigned*)&ein[b][e][((colp >> 3) ^ esw) * 8 + (colp & 7)] =
                    bf_bits(sv) | (bf_bits(cv) << 16);
                const float s2 = 2.0f * sv * cv;
                const float c2 = 1.0f - 2.0f * sv * sv;
                sv = s2; cv = c2;
            }
        }
    };

    if (ntiles > 0) issue(0);

    // GEMM1 weight fragments resident; GEMM2 frags loaded JIT in phase2
    bf16x8 w1f[2][4];
    #pragma unroll
    for (int nt = 0; nt < 2; ++nt)
        #pragma unroll
        for (int kk = 0; kk < 4; ++kk)
            w1f[nt][kk] = *(const bf16x8*)&fragbuf[((size_t)(nt * 4 + kk) * 256 + t) * 8];
    float4 b1q[2];
    #pragma unroll
    for (int nt = 0; nt < 2; ++nt)
        b1q[nt] = *(const float4*)&lb1[wv * 32 + nt * 16 + q * 4];

    if (ntiles > 0) {
        commit(0);
        do_pe(0);
        if (ntiles > 1) issue(1);
    }
    __syncthreads();  // maxbuf init + ein[0]/srow[0] ready

    for (int tt = 0; tt < ntiles; ++tt) {
        const int p = tt & 1;

        // ---- phase1: GEMM1 (swapped, W1 as A): D1[n][e] ----
        f32x4 acc[2][4];
        #pragma unroll
        for (int nt = 0; nt < 2; ++nt)
            #pragma unroll
            for (int et = 0; et < 4; ++et)
                acc[nt][et] = (f32x4){b1q[nt].x, b1q[nt].y, b1q[nt].z, b1q[nt].w};
        #pragma unroll
        for (int et = 0; et < 4; ++et) {
            const int e = et * 16 + ln;
            #pragma unroll
            for (int kk = 0; kk < 4; ++kk) {
                bf16x8 a = *(const bf16x8*)&ein[p][e][((kk * 4 + q) ^ lsw) * 8];
                acc[0][et] = __builtin_amdgcn_mfma_f32_16x16x32_bf16(w1f[0][kk], a, acc[0][et], 0, 0, 0);
                acc[1][et] = __builtin_amdgcn_mfma_f32_16x16x32_bf16(w1f[1][kk], a, acc[1][et], 0, 0, 0);
            }
        }
        if (tt + 1 < ntiles) { commit(p ^ 1); do_pe(tt + 1); }
        if (tt + 2 < ntiles) issue(tt + 2);
        // relu + b64 swizzled stores: lane holds h[e][n = wv*32+nt*16+q*4+r]
        #pragma unroll
        for (int et = 0; et < 4; ++et) {
            const int e = et * 16 + ln;
            #pragma unroll
            for (int nt = 0; nt < 2; ++nt) {
                bf16x4 hv;
                hv[0] = (__bf16)fmaxf(acc[nt][et][0], 0.0f);
                hv[1] = (__bf16)fmaxf(acc[nt][et][1], 0.0f);
                hv[2] = (__bf16)fmaxf(acc[nt][et][2], 0.0f);
                hv[3] = (__bf16)fmaxf(acc[nt][et][3], 0.0f);
                const int chunk = wv * 4 + nt * 2 + (q >> 1);
                *(bf16x4*)&hbuf[e][((chunk ^ lsw) * 8) + (q & 1) * 4] = hv;
            }
        }
        __syncthreads();  // hbuf ready; ein[p^1] committed

        // ---- phase2: GEMM2 non-swapped (h as A, W2 as B): D2[e][n] ----
        {
            bf16x8 w2f[2][4];
            #pragma unroll
            for (int nt = 0; nt < 2; ++nt)
                #pragma unroll
                for (int kk = 0; kk < 4; ++kk)
                    w2f[nt][kk] = *(const bf16x8*)&fragbuf[((size_t)(8 + nt * 4 + kk) * 256 + t) * 8];

            f32x4 acc2[4][2];
            #pragma unroll
            for (int nt = 0; nt < 2; ++nt) {
                const float b2 = lb2[wv * 32 + nt * 16 + ln];
                #pragma unroll
                for (int et = 0; et < 4; ++et)
                    acc2[et][nt] = (f32x4){b2, b2, b2, b2};
            }
            #pragma unroll
            for (int et = 0; et < 4; ++et) {
                const int e = et * 16 + ln;
                #pragma unroll
                for (int kk = 0; kk < 4; ++kk) {
                    bf16x8 ah = *(const bf16x8*)&hbuf[e][((kk * 4 + q) ^ lsw) * 8];
                    acc2[et][0] = __builtin_amdgcn_mfma_f32_16x16x32_bf16(ah, w2f[0][kk], acc2[et][0], 0, 0, 0);
                    acc2[et][1] = __builtin_amdgcn_mfma_f32_16x16x32_bf16(ah, w2f[1][kk], acc2[et][1], 0, 0, 0);
                }
            }
            // lane holds e = et*16+q*4+rr, n = wv*32+nt*16+ln: run-compress + ds_max
            const int sb = tt & 1;
            #pragma unroll
            for (int et = 0; et < 4; ++et) {
                const int4 R = *(const int4*)&srow[sb][et * 16 + q * 4];
                #pragma unroll
                for (int nt = 0; nt < 2; ++nt) {
                    unsigned* base = maxbuf + (wv * 32 + nt * 16 + ln);
                    const f32x4 vv = acc2[et][nt];
                    int cur = R.x;
                    float m = vv[0];
                    if (R.y != cur) { atomicMax(base + cur * PITCH, enc_f(m)); cur = R.y; m = vv[1]; }
                    else m = fmaxf(m, vv[1]);
                    if (R.z != cur) { atomicMax(base + cur * PITCH, enc_f(m)); cur = R.z; m = vv[2]; }
                    else m = fmaxf(m, vv[2]);
                    if (R.w != cur) { atomicMax(base + cur * PITCH, enc_f(m)); cur = R.w; m = vv[3]; }
                    else m = fmaxf(m, vv[3]);
                    atomicMax(base + cur * PITCH, enc_f(m));
                }
            }
        }
        __syncthreads();  // hbuf free; (last iter) maxbuf complete
    }

    // ---- epilogue: decode maxbuf -> afin (overlay on hbuf), final GEMM ----
    float* afin = (float*)hbuf;  // 16*128 f32 = 8 KB
    for (int i = t; i < RPB * HD; i += 256) {
        const unsigned e = maxbuf[(i >> 7) * PITCH + (i & 127)];
        afin[i] = (e == ENC_NEG_INF) ? 0.0f : dec_f(e);
    }
    __syncthreads();

    const int j4 = (t & 63) * 4;
    const int rbase = (t >> 6) * 4;
    float facc[4][4];
    const float4 bias = *(const float4*)&gb[j4];
    #pragma unroll
    for (int r = 0; r < 4; ++r) { facc[r][0] = bias.x; facc[r][1] = bias.y; facc[r][2] = bias.z; facc[r][3] = bias.w; }
    for (int k = 0; k < 128; k += 4) {
        float4 w0 = *(const float4*)&gw[(k + 0) * OD + j4];
        float4 w1 = *(const float4*)&gw[(k + 1) * OD + j4];
        float4 w2 = *(const float4*)&gw[(k + 2) * OD + j4];
        float4 w3 = *(const float4*)&gw[(k + 3) * OD + j4];
        #pragma unroll
        for (int r = 0; r < 4; ++r) {
            float4 av = *(const float4*)&afin[(rbase + r) * HD + k];
            facc[r][0] += av.x * w0.x + av.y * w1.x + av.z * w2.x + av.w * w3.x;
            facc[r][1] += av.x * w0.y + av.y * w1.y + av.z * w2.y + av.w * w3.y;
            facc[r][2] += av.x * w0.z + av.y * w1.z + av.z * w2.z + av.w * w3.z;
            facc[r][3] += av.x * w0.w + av.y * w1.w + av.z * w2.w + av.w * w3.w;
        }
    }
    #pragma unroll
    for (int r = 0; r < 4; ++r) {
        float4 v; v.x = facc[r][0]; v.y = facc[r][1]; v.z = facc[r][2]; v.w = facc[r][3];
        *(float4*)&out[(size_t)(m0 + rbase + r) * OD + j4] = v;
    }
}

extern "C" void kernel_launch(void* const* d_in, const int* in_sizes, int n_in,
                              void* d_out, int out_size, void* d_ws, size_t ws_size,
                              hipStream_t stream) {
    const float* x   = (const float*)d_in[0];
    const float* pos = (const float*)d_in[1];
    const int* batch = (const int*)d_in[2];
    const int* idx   = (const int*)d_in[3];
    const int* row   = (const int*)d_in[4];
    const int* col   = (const int*)d_in[5];
    const float* lw1 = (const float*)d_in[6];
    const float* lb1 = (const float*)d_in[7];
    const float* lw2 = (const float*)d_in[8];
    const float* lb2 = (const float*)d_in[9];
    const float* gw  = (const float*)d_in[10];
    const float* gb  = (const float*)d_in[11];
    float* out = (float*)d_out;
    __bf16* fragbuf = (__bf16*)d_ws;  // 64 KB

    hipLaunchKernelGGL(k_wprep, dim3(1), dim3(256), 0, stream, fragbuf, lw1, lw2);
    hipLaunchKernelGGL(k_prep, dim3((MM + 255) / 256), dim3(256), 0, stream, pos, batch, idx, out);
    hipLaunchKernelGGL(k_fused, dim3(MM / RPB), dim3(256), 0, stream,
                       x, pos, idx, row, col, fragbuf, lb1, lb2, gw, gb, out);
}

// Round 10
// 102.536 us; speedup vs baseline: 2.4348x; 1.1422x over previous
//
#include <hip/hip_runtime.h>
#include <math.h>

#define NN 65536
#define MM 16384
#define EE 524288
#define CF 64
#define HD 128
#define OD 256
#define RPB 16        // output rows per block
#define PITCH 129     // maxbuf row pitch (de-banked)

typedef __bf16 bf16x8 __attribute__((ext_vector_type(8)));
typedef __bf16 bf16x4 __attribute__((ext_vector_type(4)));
typedef float f32x4 __attribute__((ext_vector_type(4)));

__device__ __forceinline__ unsigned enc_f(float f) {
    unsigned u = __float_as_uint(f);
    return (u & 0x80000000u) ? ~u : (u | 0x80000000u);
}
__device__ __forceinline__ float dec_f(unsigned e) {
    unsigned u = (e & 0x80000000u) ? (e ^ 0x80000000u) : ~e;
    return __uint_as_float(u);
}
#define ENC_NEG_INF 0x007FFFFFu

__device__ __forceinline__ unsigned bf_bits(float f) {
    __bf16 b = (__bf16)f;
    return (unsigned)__builtin_bit_cast(unsigned short, b);
}

// d_ws layout: fragbuf 64 KB | rowptr 64 KB   (total 128 KB, far below proven bound)
#define WS_FRAG_OFF 0
#define WS_ROWPTR_OFF 65536

// Fused prologue: b0 = weight frags; b1-65 = rowptr binary searches; b66-129 = side outputs.
// fragbuf[fi*256 + t] (bf16x8): fi = (w2?8:0) + nt*4 + kk; element j = W[c][n],
// c = kk*32+q*8+j, n = wv*32+nt*16+ln. Column map (K permuted, weights permuted to match):
// [x:0-63][pd:64-66][zero:67][d0 pairs:68-87][d1:88-107][d2:108-127]
__global__ void k_pre(__bf16* __restrict__ fragbuf, int* __restrict__ rowptr,
                      const float* __restrict__ lw1, const float* __restrict__ lw2,
                      const int* __restrict__ row,
                      const float* __restrict__ pos, const int* __restrict__ batch,
                      const int* __restrict__ idx, float* __restrict__ out) {
    const int b = blockIdx.x;
    const int t = threadIdx.x;
    if (b == 0) {
        const int lane = t & 63;
        const int wv = t >> 6;
        const int q = lane >> 4;
        const int ln = lane & 15;
        #pragma unroll
        for (int fi = 0; fi < 16; ++fi) {
            const int nt = (fi >> 2) & 1, kk = fi & 3;
            const int n = wv * 32 + nt * 16 + ln;
            bf16x8 f;
            #pragma unroll
            for (int j = 0; j < 8; ++j) {
                const int c = kk * 32 + q * 8 + j;
                const int rk = (c < 67) ? c : c - 1;
                f[j] = (fi < 8) ? (__bf16)((c == 67) ? 0.0f : lw1[rk * HD + n])
                                : (__bf16)lw2[c * HD + n];
            }
            *(bf16x8*)&fragbuf[((size_t)fi * 256 + t) * 8] = f;
        }
    } else if (b <= 65) {
        const int i = (b - 1) * 256 + t;
        if (i <= MM) {
            int lo = 0, hi = EE;
            while (lo < hi) { int mid = (lo + hi) >> 1; if (row[mid] < i) lo = mid + 1; else hi = mid; }
            rowptr[i] = lo;
        }
    } else {
        const int m = (b - 66) * 256 + t;
        if (m < MM) {
            const int s = idx[m];
            out[MM * OD + m * 3 + 0] = pos[s * 3 + 0];
            out[MM * OD + m * 3 + 1] = pos[s * 3 + 1];
            out[MM * OD + m * 3 + 2] = pos[s * 3 + 2];
            out[MM * OD + MM * 3 + m] = (float)batch[s];
        }
    }
}

// Fully fused edge+segmax+out. Block owns rows [m0, m0+16), edges [es, ee) (contiguous).
// phase1(tt): GEMM1(einX[p], einP) -> hbuf; commit(p^1) = tile tt+1 x-data; issue(tt+2)
// phase2(tt): w2f JIT, GEMM2 non-swapped; do_pe(tt+1) -> einP/srow; segmax -> maxbuf
// epilogue: decode maxbuf -> final 128->256 GEMM -> out
__launch_bounds__(256)
__global__ void k_fused(const float* __restrict__ x, const float* __restrict__ pos,
                        const int* __restrict__ idx, const int* __restrict__ row,
                        const int* __restrict__ col, const int* __restrict__ rowptr,
                        const __bf16* __restrict__ fragbuf,
                        const float* __restrict__ lb1, const float* __restrict__ lb2,
                        const float* __restrict__ gw, const float* __restrict__ gb,
                        float* __restrict__ out) {
    __shared__ __align__(16) __bf16 einX[2][64][64];       // 16 KB (x half, dbuf)
    __shared__ __align__(16) __bf16 einP[64][64];          // 8 KB  (PE half, single)
    __shared__ __align__(16) __bf16 hbuf[64][HD];          // 16 KB (reused as afin)
    __shared__ unsigned maxbuf[(RPB + 1) * PITCH];         // 8.6 KB
    __shared__ int srow[2][64];
    const int t = threadIdx.x;
    const int lane = t & 63;
    const int wv = t >> 6;
    const int q = lane >> 4;
    const int ln = lane & 15;
    const int lsw = ln & 7;
    const int m0 = blockIdx.x * RPB;

    const int es = rowptr[m0];
    const int ee = rowptr[m0 + RPB];
    const int ntiles = (ee - es + 63) >> 6;

    for (int i = t; i < (RPB + 1) * PITCH; i += 256) maxbuf[i] = ENC_NEG_INF;

    // register staging: thread stages edge pe_e, 16-col slice pe_part
    const int pe_e = t >> 2, pe_part = t & 3, pe_esw = pe_e & 7;
    float4 v0, v1, v2, v3;
    auto issue = [&](int tt) {
        const int eg = min(es + tt * 64 + pe_e, EE - 1);
        const int c = col[eg];
        const float4* xr = (const float4*)(x + (size_t)c * CF) + pe_part * 4;
        v0 = xr[0]; v1 = xr[1]; v2 = xr[2]; v3 = xr[3];
    };
    auto commit = [&](int b) {
        bf16x8 pk;
        pk[0] = (__bf16)v0.x; pk[1] = (__bf16)v0.y; pk[2] = (__bf16)v0.z; pk[3] = (__bf16)v0.w;
        pk[4] = (__bf16)v1.x; pk[5] = (__bf16)v1.y; pk[6] = (__bf16)v1.z; pk[7] = (__bf16)v1.w;
        *(bf16x8*)&einX[b][pe_e][((pe_part * 2 + 0) ^ pe_esw) * 8] = pk;
        pk[0] = (__bf16)v2.x; pk[1] = (__bf16)v2.y; pk[2] = (__bf16)v2.z; pk[3] = (__bf16)v2.w;
        pk[4] = (__bf16)v3.x; pk[5] = (__bf16)v3.y; pk[6] = (__bf16)v3.z; pk[7] = (__bf16)v3.w;
        *(bf16x8*)&einX[b][pe_e][((pe_part * 2 + 1) ^ pe_esw) * 8] = pk;
    };
    // PE: one fract+sin+cos then 9 double-angle steps; writes einP (cols-64) + srow
    auto do_pe = [&](int tt) {
        if (t < 192) {
            const int e = t & 63, d = t >> 6;
            const int sb = tt & 1;
            const int eidx = es + tt * 64 + e;
            const int eg = min(eidx, EE - 1);
            const int r = row[eg];
            const int c = col[eg];
            const int s = idx[r];
            const int esw = e & 7;
            const float pd = pos[c * 3 + d] - pos[s * 3 + d];
            if (d == 0) {
                srow[sb][e] = (eidx < ee) ? (r - m0) : RPB;  // dummy row for tails
                const float pd1 = pos[c * 3 + 1] - pos[s * 3 + 1];
                const float pd2 = pos[c * 3 + 2] - pos[s * 3 + 2];
                uint2 pkt;
                pkt.x = bf_bits(pd) | (bf_bits(pd1) << 16);
                pkt.y = bf_bits(pd2);  // col 67 = 0
                *(uint2*)&einP[e][esw * 8] = pkt;  // jP 0-3 in chunk 0^esw
            }
            const float fr = __builtin_amdgcn_fractf(pd * 0.5f);
            float sv = __builtin_amdgcn_sinf(fr);
            float cv = __builtin_amdgcn_cosf(fr);
            #pragma unroll
            for (int l = 0; l < 10; ++l) {
                const int jP = 4 + d * 20 + l * 2;  // column-64
                *(unsigned*)&einP[e][((jP >> 3) ^ esw) * 8 + (jP & 7)] =
                    bf_bits(sv) | (bf_bits(cv) << 16);
                const float s2 = 2.0f * sv * cv;
                const float c2 = 1.0f - 2.0f * sv * sv;
                sv = s2; cv = c2;
            }
        }
    };

    if (ntiles > 0) issue(0);

    // GEMM1 weight fragments resident; GEMM2 frags loaded JIT in phase2
    bf16x8 w1f[2][4];
    #pragma unroll
    for (int nt = 0; nt < 2; ++nt)
        #pragma unroll
        for (int kk = 0; kk < 4; ++kk)
            w1f[nt][kk] = *(const bf16x8*)&fragbuf[((size_t)(nt * 4 + kk) * 256 + t) * 8];
    float4 b1q[2];
    #pragma unroll
    for (int nt = 0; nt < 2; ++nt)
        b1q[nt] = *(const float4*)&lb1[wv * 32 + nt * 16 + q * 4];

    if (ntiles > 0) {
        commit(0);
        do_pe(0);
        if (ntiles > 1) issue(1);
    }
    __syncthreads();  // maxbuf init + einX[0]/einP/srow[0] ready

    for (int tt = 0; tt < ntiles; ++tt) {
        const int p = tt & 1;

        // ---- phase1: GEMM1 (swapped, W1 as A): D1[n][e] ----
        f32x4 acc[2][4];
        #pragma unroll
        for (int nt = 0; nt < 2; ++nt)
            #pragma unroll
            for (int et = 0; et < 4; ++et)
                acc[nt][et] = (f32x4){b1q[nt].x, b1q[nt].y, b1q[nt].z, b1q[nt].w};
        #pragma unroll
        for (int et = 0; et < 4; ++et) {
            const int e = et * 16 + ln;
            bf16x8 a[4];
            a[0] = *(const bf16x8*)&einX[p][e][(q ^ lsw) * 8];
            a[1] = *(const bf16x8*)&einX[p][e][((4 + q) ^ lsw) * 8];
            a[2] = *(const bf16x8*)&einP[e][(q ^ lsw) * 8];
            a[3] = *(const bf16x8*)&einP[e][((4 + q) ^ lsw) * 8];
            #pragma unroll
            for (int kk = 0; kk < 4; ++kk) {
                acc[0][et] = __builtin_amdgcn_mfma_f32_16x16x32_bf16(w1f[0][kk], a[kk], acc[0][et], 0, 0, 0);
                acc[1][et] = __builtin_amdgcn_mfma_f32_16x16x32_bf16(w1f[1][kk], a[kk], acc[1][et], 0, 0, 0);
            }
        }
        // stage tile tt+1 x-data into the other einX buffer (reads drained 2 barriers ago)
        if (tt + 1 < ntiles) commit(p ^ 1);
        if (tt + 2 < ntiles) issue(tt + 2);
        // relu + b64 swizzled stores: lane holds h[e][n = wv*32+nt*16+q*4+r]
        #pragma unroll
        for (int et = 0; et < 4; ++et) {
            const int e = et * 16 + ln;
            #pragma unroll
            for (int nt = 0; nt < 2; ++nt) {
                bf16x4 hv;
                hv[0] = (__bf16)fmaxf(acc[nt][et][0], 0.0f);
                hv[1] = (__bf16)fmaxf(acc[nt][et][1], 0.0f);
                hv[2] = (__bf16)fmaxf(acc[nt][et][2], 0.0f);
                hv[3] = (__bf16)fmaxf(acc[nt][et][3], 0.0f);
                const int chunk = wv * 4 + nt * 2 + (q >> 1);
                *(bf16x4*)&hbuf[e][((chunk ^ lsw) * 8) + (q & 1) * 4] = hv;
            }
        }
        __syncthreads();  // hbuf ready; einX[p]/einP phase1 reads drained

        // ---- phase2 ----
        {
            bf16x8 w2f[2][4];
            #pragma unroll
            for (int nt = 0; nt < 2; ++nt)
                #pragma unroll
                for (int kk = 0; kk < 4; ++kk)
                    w2f[nt][kk] = *(const bf16x8*)&fragbuf[((size_t)(8 + nt * 4 + kk) * 256 + t) * 8];

            // GEMM2 non-swapped (h as A, W2 as B): D2[e][n]
            f32x4 acc2[4][2];
            #pragma unroll
            for (int nt = 0; nt < 2; ++nt) {
                const float b2 = lb2[wv * 32 + nt * 16 + ln];
                #pragma unroll
                for (int et = 0; et < 4; ++et)
                    acc2[et][nt] = (f32x4){b2, b2, b2, b2};
            }
            #pragma unroll
            for (int et = 0; et < 4; ++et) {
                const int e = et * 16 + ln;
                #pragma unroll
                for (int kk = 0; kk < 4; ++kk) {
                    bf16x8 ah = *(const bf16x8*)&hbuf[e][((kk * 4 + q) ^ lsw) * 8];
                    acc2[et][0] = __builtin_amdgcn_mfma_f32_16x16x32_bf16(ah, w2f[0][kk], acc2[et][0], 0, 0, 0);
                    acc2[et][1] = __builtin_amdgcn_mfma_f32_16x16x32_bf16(ah, w2f[1][kk], acc2[et][1], 0, 0, 0);
                }
            }
            if (tt + 1 < ntiles) do_pe(tt + 1);  // einP reads drained; srow[sb^1]
            // lane holds e = et*16+q*4+rr, n = wv*32+nt*16+ln: run-compress + ds_max
            const int sb = tt & 1;
            #pragma unroll
            for (int et = 0; et < 4; ++et) {
                const int4 R = *(const int4*)&srow[sb][et * 16 + q * 4];
                #pragma unroll
                for (int nt = 0; nt < 2; ++nt) {
                    unsigned* base = maxbuf + (wv * 32 + nt * 16 + ln);
                    const f32x4 vv = acc2[et][nt];
                    int cur = R.x;
                    float m = vv[0];
                    if (R.y != cur) { atomicMax(base + cur * PITCH, enc_f(m)); cur = R.y; m = vv[1]; }
                    else m = fmaxf(m, vv[1]);
                    if (R.z != cur) { atomicMax(base + cur * PITCH, enc_f(m)); cur = R.z; m = vv[2]; }
                    else m = fmaxf(m, vv[2]);
                    if (R.w != cur) { atomicMax(base + cur * PITCH, enc_f(m)); cur = R.w; m = vv[3]; }
                    else m = fmaxf(m, vv[3]);
                    atomicMax(base + cur * PITCH, enc_f(m));
                }
            }
        }
        __syncthreads();  // hbuf free; einP(tt+1)/srow ready; (last) maxbuf complete
    }

    // ---- epilogue: decode maxbuf -> afin (overlay on hbuf), final GEMM ----
    float* afin = (float*)hbuf;  // 16*128 f32 = 8 KB
    for (int i = t; i < RPB * HD; i += 256) {
        const unsigned e = maxbuf[(i >> 7) * PITCH + (i & 127)];
        afin[i] = (e == ENC_NEG_INF) ? 0.0f : dec_f(e);
    }
    __syncthreads();

    const int j4 = (t & 63) * 4;
    const int rbase = (t >> 6) * 4;
    float facc[4][4];
    const float4 bias = *(const float4*)&gb[j4];
    #pragma unroll
    for (int r = 0; r < 4; ++r) { facc[r][0] = bias.x; facc[r][1] = bias.y; facc[r][2] = bias.z; facc[r][3] = bias.w; }
    for (int k = 0; k < 128; k += 4) {
        float4 w0 = *(const float4*)&gw[(k + 0) * OD + j4];
        float4 w1 = *(const float4*)&gw[(k + 1) * OD + j4];
        float4 w2 = *(const float4*)&gw[(k + 2) * OD + j4];
        float4 w3 = *(const float4*)&gw[(k + 3) * OD + j4];
        #pragma unroll
        for (int r = 0; r < 4; ++r) {
            float4 av = *(const float4*)&afin[(rbase + r) * HD + k];
            facc[r][0] += av.x * w0.x + av.y * w1.x + av.z * w2.x + av.w * w3.x;
            facc[r][1] += av.x * w0.y + av.y * w1.y + av.z * w2.y + av.w * w3.y;
            facc[r][2] += av.x * w0.z + av.y * w1.z + av.z * w2.z + av.w * w3.z;
            facc[r][3] += av.x * w0.w + av.y * w1.w + av.z * w2.w + av.w * w3.w;
        }
    }
    #pragma unroll
    for (int r = 0; r < 4; ++r) {
        float4 v; v.x = facc[r][0]; v.y = facc[r][1]; v.z = facc[r][2]; v.w = facc[r][3];
        *(float4*)&out[(size_t)(m0 + rbase + r) * OD + j4] = v;
    }
}

extern "C" void kernel_launch(void* const* d_in, const int* in_sizes, int n_in,
                              void* d_out, int out_size, void* d_ws, size_t ws_size,
                              hipStream_t stream) {
    const float* x   = (const float*)d_in[0];
    const float* pos = (const float*)d_in[1];
    const int* batch = (const int*)d_in[2];
    const int* idx   = (const int*)d_in[3];
    const int* row   = (const int*)d_in[4];
    const int* col   = (const int*)d_in[5];
    const float* lw1 = (const float*)d_in[6];
    const float* lb1 = (const float*)d_in[7];
    const float* lw2 = (const float*)d_in[8];
    const float* lb2 = (const float*)d_in[9];
    const float* gw  = (const float*)d_in[10];
    const float* gb  = (const float*)d_in[11];
    float* out = (float*)d_out;
    __bf16* fragbuf = (__bf16*)((char*)d_ws + WS_FRAG_OFF);
    int* rowptr     = (int*)((char*)d_ws + WS_ROWPTR_OFF);

    hipLaunchKernelGGL(k_pre, dim3(1 + 65 + 64), dim3(256), 0, stream,
                       fragbuf, rowptr, lw1, lw2, row, pos, batch, idx, out);
    hipLaunchKernelGGL(k_fused, dim3(MM / RPB), dim3(256), 0, stream,
                       x, pos, idx, row, col, rowptr, fragbuf, lb1, lb2, gw, gb, out);
}

// Round 11
// 99.772 us; speedup vs baseline: 2.5022x; 1.0277x over previous
//
#include <hip/hip_runtime.h>
#include <math.h>

#define NN 65536
#define MM 16384
#define EE 524288
#define CF 64
#define HD 128
#define OD 256
#define RPB 16        // output rows per block
#define PITCH 129     // maxbuf row pitch (de-banked)

typedef __bf16 bf16x8 __attribute__((ext_vector_type(8)));
typedef __bf16 bf16x4 __attribute__((ext_vector_type(4)));
typedef float f32x4 __attribute__((ext_vector_type(4)));

__device__ __forceinline__ unsigned enc_f(float f) {
    unsigned u = __float_as_uint(f);
    return (u & 0x80000000u) ? ~u : (u | 0x80000000u);
}
__device__ __forceinline__ float dec_f(unsigned e) {
    unsigned u = (e & 0x80000000u) ? (e ^ 0x80000000u) : ~e;
    return __uint_as_float(u);
}
#define ENC_NEG_INF 0x007FFFFFu

__device__ __forceinline__ unsigned bf_bits(float f) {
    __bf16 b = (__bf16)f;
    return (unsigned)__builtin_bit_cast(unsigned short, b);
}

// d_ws layout (proven >= 134 MB usable in R4): frag 64K | rowptr 64K | xbf 8M | pd 8M
#define WS_FRAG_OFF 0
#define WS_ROWPTR_OFF 65536
#define WS_XBF_OFF 131072
#define WS_PD_OFF (131072 + 8388608)

// Fused prologue:
// b0: weight frags; b1-65: rowptr; b66-129: side outputs; b130-1153: x->bf16; b1154+: pd.
// fragbuf[fi*256 + t] (bf16x8): fi = (w2?8:0) + nt*4 + kk; element j = W[c][n],
// c = kk*32+q*8+j, n = wv*32+nt*16+ln. Column map (K permuted, weights permuted to match):
// [x:0-63][pd:64-66][zero:67][d0 pairs:68-87][d1:88-107][d2:108-127]
__global__ void k_pre(__bf16* __restrict__ fragbuf, int* __restrict__ rowptr,
                      __bf16* __restrict__ xbf, float4* __restrict__ pdbuf,
                      const float* __restrict__ lw1, const float* __restrict__ lw2,
                      const float* __restrict__ x, const int* __restrict__ row,
                      const int* __restrict__ col,
                      const float* __restrict__ pos, const int* __restrict__ batch,
                      const int* __restrict__ idx, float* __restrict__ out) {
    const int b = blockIdx.x;
    const int t = threadIdx.x;
    if (b == 0) {
        const int lane = t & 63;
        const int wv = t >> 6;
        const int q = lane >> 4;
        const int ln = lane & 15;
        #pragma unroll
        for (int fi = 0; fi < 16; ++fi) {
            const int nt = (fi >> 2) & 1, kk = fi & 3;
            const int n = wv * 32 + nt * 16 + ln;
            bf16x8 f;
            #pragma unroll
            for (int j = 0; j < 8; ++j) {
                const int c = kk * 32 + q * 8 + j;
                const int rk = (c < 67) ? c : c - 1;
                f[j] = (fi < 8) ? (__bf16)((c == 67) ? 0.0f : lw1[rk * HD + n])
                                : (__bf16)lw2[c * HD + n];
            }
            *(bf16x8*)&fragbuf[((size_t)fi * 256 + t) * 8] = f;
        }
    } else if (b <= 65) {
        const int i = (b - 1) * 256 + t;
        if (i <= MM) {
            int lo = 0, hi = EE;
            while (lo < hi) { int mid = (lo + hi) >> 1; if (row[mid] < i) lo = mid + 1; else hi = mid; }
            rowptr[i] = lo;
        }
    } else if (b <= 129) {
        const int m = (b - 66) * 256 + t;
        if (m < MM) {
            const int s = idx[m];
            out[MM * OD + m * 3 + 0] = pos[s * 3 + 0];
            out[MM * OD + m * 3 + 1] = pos[s * 3 + 1];
            out[MM * OD + m * 3 + 2] = pos[s * 3 + 2];
            out[MM * OD + MM * 3 + m] = (float)batch[s];
        }
    } else if (b <= 1153) {
        const size_t base = ((size_t)(b - 130) * 256 + t) * 16;
        const float4* xs = (const float4*)(x + base);
        const float4 a = xs[0], c = xs[1], d = xs[2], e = xs[3];
        bf16x8 o0, o1;
        o0[0] = (__bf16)a.x; o0[1] = (__bf16)a.y; o0[2] = (__bf16)a.z; o0[3] = (__bf16)a.w;
        o0[4] = (__bf16)c.x; o0[5] = (__bf16)c.y; o0[6] = (__bf16)c.z; o0[7] = (__bf16)c.w;
        o1[0] = (__bf16)d.x; o1[1] = (__bf16)d.y; o1[2] = (__bf16)d.z; o1[3] = (__bf16)d.w;
        o1[4] = (__bf16)e.x; o1[5] = (__bf16)e.y; o1[6] = (__bf16)e.z; o1[7] = (__bf16)e.w;
        *(bf16x8*)&xbf[base] = o0;
        *(bf16x8*)&xbf[base + 8] = o1;
    } else {
        const int e = (b - 1154) * 256 + t;  // exactly EE threads
        const int r = row[e];
        const int c = col[e];
        const int s = idx[r];
        float4 pd;
        pd.x = pos[c * 3 + 0] - pos[s * 3 + 0];
        pd.y = pos[c * 3 + 1] - pos[s * 3 + 1];
        pd.z = pos[c * 3 + 2] - pos[s * 3 + 2];
        pd.w = 0.0f;
        pdbuf[e] = pd;
    }
}

// Fully fused edge+segmax+out. Block owns rows [m0, m0+16), edges [es, ee) (contiguous).
// phase1(tt): GEMM1(einX, einP) -> hbuf; issue(tt+1) from xbf
// phase2(tt): commit(tt+1)->einX; w2f JIT; GEMM2 non-swapped; do_pe(tt+1)->einP/srow;
//             run-compress segmax -> ds_atomicMax maxbuf
// epilogue: decode maxbuf -> final 128->256 GEMM -> out
__launch_bounds__(256)
__global__ void k_fused(const __bf16* __restrict__ xbf, const float4* __restrict__ pdbuf,
                        const int* __restrict__ row, const int* __restrict__ col,
                        const int* __restrict__ rowptr, const __bf16* __restrict__ fragbuf,
                        const float* __restrict__ lb1, const float* __restrict__ lb2,
                        const float* __restrict__ gw, const float* __restrict__ gb,
                        float* __restrict__ out) {
    __shared__ __align__(16) __bf16 einX[64][64];          // 8 KB (x half, single buffer)
    __shared__ __align__(16) __bf16 einP[64][64];          // 8 KB (PE half, single buffer)
    __shared__ __align__(16) __bf16 hbuf[64][HD];          // 16 KB (reused as afin)
    __shared__ unsigned maxbuf[(RPB + 1) * PITCH];         // 8.6 KB
    __shared__ int srow[2][64];
    const int t = threadIdx.x;
    const int lane = t & 63;
    const int wv = t >> 6;
    const int q = lane >> 4;
    const int ln = lane & 15;
    const int lsw = ln & 7;
    const int m0 = blockIdx.x * RPB;

    const int es = rowptr[m0];
    const int ee = rowptr[m0 + RPB];
    const int ntiles = (ee - es + 63) >> 6;

    for (int i = t; i < (RPB + 1) * PITCH; i += 256) maxbuf[i] = ENC_NEG_INF;

    // register staging from xbf: thread stages edge pe_e, 16-col slice pe_part
    const int pe_e = t >> 2, pe_part = t & 3, pe_esw = pe_e & 7;
    bf16x8 s0, s1;
    auto issue = [&](int tt) {
        const int eg = min(es + tt * 64 + pe_e, EE - 1);
        const int c = col[eg];
        const bf16x8* xr = (const bf16x8*)(xbf + (size_t)c * CF) + pe_part * 2;
        s0 = xr[0]; s1 = xr[1];
    };
    auto commit = [&]() {
        *(bf16x8*)&einX[pe_e][((pe_part * 2 + 0) ^ pe_esw) * 8] = s0;
        *(bf16x8*)&einX[pe_e][((pe_part * 2 + 1) ^ pe_esw) * 8] = s1;
    };
    // PE: pd from pdbuf (no gather chain); one fract+sin+cos + 9 double-angle steps
    auto do_pe = [&](int tt) {
        if (t < 192) {
            const int e = t & 63, d = t >> 6;
            const int sb = tt & 1;
            const int eidx = es + tt * 64 + e;
            const int eg = min(eidx, EE - 1);
            const int esw = e & 7;
            const float4 P = pdbuf[eg];
            const float pd = (d == 0) ? P.x : ((d == 1) ? P.y : P.z);
            if (d == 0) {
                srow[sb][e] = (eidx < ee) ? (row[eg] - m0) : RPB;  // dummy row for tails
                uint2 pkt;
                pkt.x = bf_bits(P.x) | (bf_bits(P.y) << 16);
                pkt.y = bf_bits(P.z);  // col 67 = 0
                *(uint2*)&einP[e][esw * 8] = pkt;  // jP 0-3 in chunk 0^esw
            }
            const float fr = __builtin_amdgcn_fractf(pd * 0.5f);
            float sv = __builtin_amdgcn_sinf(fr);
            float cv = __builtin_amdgcn_cosf(fr);
            #pragma unroll
            for (int l = 0; l < 10; ++l) {
                const int jP = 4 + d * 20 + l * 2;  // column-64
                *(unsigned*)&einP[e][((jP >> 3) ^ esw) * 8 + (jP & 7)] =
                    bf_bits(sv) | (bf_bits(cv) << 16);
                const float s2 = 2.0f * sv * cv;
                const float c2 = 1.0f - 2.0f * sv * sv;
                sv = s2; cv = c2;
            }
        }
    };

    // GEMM1 weight fragments resident; GEMM2 frags loaded JIT in phase2
    bf16x8 w1f[2][4];
    #pragma unroll
    for (int nt = 0; nt < 2; ++nt)
        #pragma unroll
        for (int kk = 0; kk < 4; ++kk)
            w1f[nt][kk] = *(const bf16x8*)&fragbuf[((size_t)(nt * 4 + kk) * 256 + t) * 8];
    float4 b1q[2];
    #pragma unroll
    for (int nt = 0; nt < 2; ++nt)
        b1q[nt] = *(const float4*)&lb1[wv * 32 + nt * 16 + q * 4];

    if (ntiles > 0) {
        issue(0);
        commit();
        do_pe(0);
        if (ntiles > 1) issue(1);  // consumed by commit in phase2(0)
    }
    __syncthreads();  // maxbuf init + einX/einP/srow[0] ready

    for (int tt = 0; tt < ntiles; ++tt) {
        // ---- phase1: GEMM1 (swapped, W1 as A): D1[n][e] ----
        f32x4 acc[2][4];
        #pragma unroll
        for (int nt = 0; nt < 2; ++nt)
            #pragma unroll
            for (int et = 0; et < 4; ++et)
                acc[nt][et] = (f32x4){b1q[nt].x, b1q[nt].y, b1q[nt].z, b1q[nt].w};
        #pragma unroll
        for (int et = 0; et < 4; ++et) {
            const int e = et * 16 + ln;
            bf16x8 a[4];
            a[0] = *(const bf16x8*)&einX[e][(q ^ lsw) * 8];
            a[1] = *(const bf16x8*)&einX[e][((4 + q) ^ lsw) * 8];
            a[2] = *(const bf16x8*)&einP[e][(q ^ lsw) * 8];
            a[3] = *(const bf16x8*)&einP[e][((4 + q) ^ lsw) * 8];
            #pragma unroll
            for (int kk = 0; kk < 4; ++kk) {
                acc[0][et] = __builtin_amdgcn_mfma_f32_16x16x32_bf16(w1f[0][kk], a[kk], acc[0][et], 0, 0, 0);
                acc[1][et] = __builtin_amdgcn_mfma_f32_16x16x32_bf16(w1f[1][kk], a[kk], acc[1][et], 0, 0, 0);
            }
        }
        // relu + b64 swizzled stores: lane holds h[e][n = wv*32+nt*16+q*4+r]
        #pragma unroll
        for (int et = 0; et < 4; ++et) {
            const int e = et * 16 + ln;
            #pragma unroll
            for (int nt = 0; nt < 2; ++nt) {
                bf16x4 hv;
                hv[0] = (__bf16)fmaxf(acc[nt][et][0], 0.0f);
                hv[1] = (__bf16)fmaxf(acc[nt][et][1], 0.0f);
                hv[2] = (__bf16)fmaxf(acc[nt][et][2], 0.0f);
                hv[3] = (__bf16)fmaxf(acc[nt][et][3], 0.0f);
                const int chunk = wv * 4 + nt * 2 + (q >> 1);
                *(bf16x4*)&hbuf[e][((chunk ^ lsw) * 8) + (q & 1) * 4] = hv;
            }
        }
        __syncthreads();  // hbuf ready; einX/einP phase1 reads drained

        // ---- phase2 ----
        {
            if (tt + 1 < ntiles) { commit(); issue(tt + 2 < ntiles ? tt + 2 : tt + 1); }
            bf16x8 w2f[2][4];
            #pragma unroll
            for (int nt = 0; nt < 2; ++nt)
                #pragma unroll
                for (int kk = 0; kk < 4; ++kk)
                    w2f[nt][kk] = *(const bf16x8*)&fragbuf[((size_t)(8 + nt * 4 + kk) * 256 + t) * 8];

            // GEMM2 non-swapped (h as A, W2 as B): D2[e][n]
            f32x4 acc2[4][2];
            #pragma unroll
            for (int nt = 0; nt < 2; ++nt) {
                const float b2 = lb2[wv * 32 + nt * 16 + ln];
                #pragma unroll
                for (int et = 0; et < 4; ++et)
                    acc2[et][nt] = (f32x4){b2, b2, b2, b2};
            }
            #pragma unroll
            for (int et = 0; et < 4; ++et) {
                const int e = et * 16 + ln;
                #pragma unroll
                for (int kk = 0; kk < 4; ++kk) {
                    bf16x8 ah = *(const bf16x8*)&hbuf[e][((kk * 4 + q) ^ lsw) * 8];
                    acc2[et][0] = __builtin_amdgcn_mfma_f32_16x16x32_bf16(ah, w2f[0][kk], acc2[et][0], 0, 0, 0);
                    acc2[et][1] = __builtin_amdgcn_mfma_f32_16x16x32_bf16(ah, w2f[1][kk], acc2[et][1], 0, 0, 0);
                }
            }
            if (tt + 1 < ntiles) do_pe(tt + 1);  // einP phase1 reads drained; srow[sb^1]
            // lane holds e = et*16+q*4+rr, n = wv*32+nt*16+ln: run-compress + ds_max
            const int sb = tt & 1;
            #pragma unroll
            for (int et = 0; et < 4; ++et) {
                const int4 R = *(const int4*)&srow[sb][et * 16 + q * 4];
                #pragma unroll
                for (int nt = 0; nt < 2; ++nt) {
                    unsigned* base = maxbuf + (wv * 32 + nt * 16 + ln);
                    const f32x4 vv = acc2[et][nt];
                    int cur = R.x;
                    float m = vv[0];
                    if (R.y != cur) { atomicMax(base + cur * PITCH, enc_f(m)); cur = R.y; m = vv[1]; }
                    else m = fmaxf(m, vv[1]);
                    if (R.z != cur) { atomicMax(base + cur * PITCH, enc_f(m)); cur = R.z; m = vv[2]; }
                    else m = fmaxf(m, vv[2]);
                    if (R.w != cur) { atomicMax(base + cur * PITCH, enc_f(m)); cur = R.w; m = vv[3]; }
                    else m = fmaxf(m, vv[3]);
                    atomicMax(base + cur * PITCH, enc_f(m));
                }
            }
        }
        __syncthreads();  // einX/einP(tt+1)/srow ready; hbuf free; (last) maxbuf complete
    }

    // ---- epilogue: decode maxbuf -> afin (overlay on hbuf), final GEMM ----
    float* afin = (float*)hbuf;  // 16*128 f32 = 8 KB
    for (int i = t; i < RPB * HD; i += 256) {
        const unsigned e = maxbuf[(i >> 7) * PITCH + (i & 127)];
        afin[i] = (e == ENC_NEG_INF) ? 0.0f : dec_f(e);
    }
    __syncthreads();

    const int j4 = (t & 63) * 4;
    const int rbase = (t >> 6) * 4;
    float facc[4][4];
    const float4 bias = *(const float4*)&gb[j4];
    #pragma unroll
    for (int r = 0; r < 4; ++r) { facc[r][0] = bias.x; facc[r][1] = bias.y; facc[r][2] = bias.z; facc[r][3] = bias.w; }
    for (int k = 0; k < 128; k += 4) {
        float4 w0 = *(const float4*)&gw[(k + 0) * OD + j4];
        float4 w1 = *(const float4*)&gw[(k + 1) * OD + j4];
        float4 w2 = *(const float4*)&gw[(k + 2) * OD + j4];
        float4 w3 = *(const float4*)&gw[(k + 3) * OD + j4];
        #pragma unroll
        for (int r = 0; r < 4; ++r) {
            float4 av = *(const float4*)&afin[(rbase + r) * HD + k];
            facc[r][0] += av.x * w0.x + av.y * w1.x + av.z * w2.x + av.w * w3.x;
            facc[r][1] += av.x * w0.y + av.y * w1.y + av.z * w2.y + av.w * w3.y;
            facc[r][2] += av.x * w0.z + av.y * w1.z + av.z * w2.z + av.w * w3.z;
            facc[r][3] += av.x * w0.w + av.y * w1.w + av.z * w2.w + av.w * w3.w;
        }
    }
    #pragma unroll
    for (int r = 0; r < 4; ++r) {
        float4 v; v.x = facc[r][0]; v.y = facc[r][1]; v.z = facc[r][2]; v.w = facc[r][3];
        *(float4*)&out[(size_t)(m0 + rbase + r) * OD + j4] = v;
    }
}

extern "C" void kernel_launch(void* const* d_in, const int* in_sizes, int n_in,
                              void* d_out, int out_size, void* d_ws, size_t ws_size,
                              hipStream_t stream) {
    const float* x   = (const float*)d_in[0];
    const float* pos = (const float*)d_in[1];
    const int* batch = (const int*)d_in[2];
    const int* idx   = (const int*)d_in[3];
    const int* row   = (const int*)d_in[4];
    const int* col   = (const int*)d_in[5];
    const float* lw1 = (const float*)d_in[6];
    const float* lb1 = (const float*)d_in[7];
    const float* lw2 = (const float*)d_in[8];
    const float* lb2 = (const float*)d_in[9];
    const float* gw  = (const float*)d_in[10];
    const float* gb  = (const float*)d_in[11];
    float* out = (float*)d_out;
    __bf16* fragbuf = (__bf16*)((char*)d_ws + WS_FRAG_OFF);
    int* rowptr     = (int*)((char*)d_ws + WS_ROWPTR_OFF);
    __bf16* xbf     = (__bf16*)((char*)d_ws + WS_XBF_OFF);
    float4* pdbuf   = (float4*)((char*)d_ws + WS_PD_OFF);

    hipLaunchKernelGGL(k_pre, dim3(1 + 65 + 64 + 1024 + 2048), dim3(256), 0, stream,
                       fragbuf, rowptr, xbf, pdbuf, lw1, lw2, x, row, col, pos, batch, idx, out);
    hipLaunchKernelGGL(k_fused, dim3(MM / RPB), dim3(256), 0, stream,
                       xbf, pdbuf, row, col, rowptr, fragbuf, lb1, lb2, gw, gb, out);
}